// Round 10
// baseline (429.294 us; speedup 1.0000x reference)
//
#include <hip/hip_runtime.h>

// GCN: 2x GCNConv(sym-norm, self-loops) + mean-pool + 2 MLP heads.
// R12: R11's 4-deep batched gathers + L2-window protection. R9 lesson:
// batching raises BW 2.8->3.6TB/s but streaming pollution re-fetches 36%
// of the sweep (FETCH 198->269MB). Fix: NT-load the edata stream (read
// once, evict-first) and NT-store agg2 (never gathered); gather operands
// (Xp, h2) and h2's store stay PLAIN (R6: NT on a gathered array is toxic).
// Carried: tile-phased lockstep sweep (R4/R5), 16B Xp operand in aggA
// (R7), LDS sorts + coalesced writeout (R3/R4), no float LDS atomics
// (R2), binA CHUNK=8192 (R7), sequential A-then-B run loops (R8 lesson).

#define NBUCK 512          // coarse buckets = dst >> 9
#define BCAP  10240        // slack capacity per bucket (mean 8192, sigma ~90)
#define CHUNK 8192         // edges per pass-A block (16 per bucket avg)
#define APT   16           // edges per thread in binA (CHUNK/512)
#define NTILE 8            // src tiles = src >> 15
#define TSH   15
#define RCAP  20           // BCAP/512 register-staged edges per thread

__device__ __forceinline__ float leaky(float x) { return x > 0.f ? x : 0.01f * x; }

typedef float __attribute__((ext_vector_type(4))) f32x4;

// edata as read-once stream: 8B NT load (evict-first; protects L2 window)
__device__ __forceinline__ int2 nt_edge(const int2* p) {
    long long raw = __builtin_nontemporal_load((const long long*)p);
    int2 r; r.x = (int)(unsigned)(raw & 0xFFFFFFFFll); r.y = (int)(raw >> 32);
    return r;
}
__device__ __forceinline__ void nt_store4(float a, float b, float c, float d, float* dst) {
    f32x4 v = {a, b, c, d};
    __builtin_nontemporal_store(v, (f32x4*)dst);
}

// --- Pass A: bin edges by dst>>9 into slack-capacity coarse buckets ------
__global__ __launch_bounds__(512) void
binA_kernel(const int* __restrict__ src, const int* __restrict__ dst,
            const float* __restrict__ ew, int* __restrict__ bucketCursor,
            int2* __restrict__ coarse, int E) {
    __shared__ int lhist[NBUCK], lbase[NBUCK], lcur[NBUCK], gbase[NBUCK];
    __shared__ int tmp[NBUCK];
    __shared__ int2 stag[CHUNK];              // 64 KB
    __shared__ unsigned short sbuck[CHUNK];   // 16 KB
    int t = threadIdx.x;
    int base = blockIdx.x * CHUNK;
    lhist[t] = 0; lcur[t] = 0;
    __syncthreads();
    int n = min(CHUNK, E - base);
    int myDst[APT], mySrc[APT]; float myEw[APT];
#pragma unroll
    for (int k = 0; k < APT; ++k) {
        int j = t + k * 512;                  // coalesced
        if (j < n) {
            int d = dst[base + j];
            myDst[k] = d; mySrc[k] = src[base + j]; myEw[k] = ew[base + j];
            atomicAdd(&lhist[d >> 9], 1);
        } else myDst[k] = -1;
    }
    __syncthreads();
    // exclusive scan of lhist (512 entries, 512 threads)
    int hv = lhist[t];
    tmp[t] = hv;
    __syncthreads();
    for (int off = 1; off < NBUCK; off <<= 1) {
        int v = (t >= off) ? tmp[t - off] : 0;
        __syncthreads();
        tmp[t] += v;
        __syncthreads();
    }
    lbase[t] = tmp[t] - hv;
    gbase[t] = hv ? atomicAdd(&bucketCursor[t], hv) : 0;
    __syncthreads();
    // stage into LDS, sorted by bucket; pack (src | ldst<<18, ew)
#pragma unroll
    for (int k = 0; k < APT; ++k) {
        int d = myDst[k];
        if (d >= 0) {
            int b = d >> 9;
            int p = lbase[b] + atomicAdd(&lcur[b], 1);
            stag[p] = make_int2(mySrc[k] | ((d & 511) << 18), __float_as_int(myEw[k]));
            sbuck[p] = (unsigned short)b;
        }
    }
    __syncthreads();
    // write out: consecutive j -> consecutive addresses within bucket runs
    for (int j = t; j < n; j += 512) {
        int b = sbuck[j];
        coarse[(size_t)b * BCAP + gbase[b] + (j - lbase[b])] = stag[j];
    }
}

// --- scan bucket counts -> bucket bases (1 block x 512) ------------------
__global__ void bscan_kernel(const int* __restrict__ bucketCursor,
                             int* __restrict__ bucketBase, int* __restrict__ row,
                             int N, int E) {
    __shared__ int s[NBUCK];
    int t = threadIdx.x;
    int v = bucketCursor[t];
    s[t] = v;
    __syncthreads();
    for (int off = 1; off < NBUCK; off <<= 1) {
        int x = (t >= off) ? s[t - off] : 0;
        __syncthreads();
        s[t] += x;
        __syncthreads();
    }
    bucketBase[t] = s[t] - v;
    if (t == 0) row[N] = E;
}

// --- Pass B: LDS-staged (ld,tile) counting sort; coalesced writeout ------
__global__ __launch_bounds__(512, 2) void
binB_kernel(const int* __restrict__ bucketCursor, const int* __restrict__ bucketBase,
            const int2* __restrict__ coarse, int2* __restrict__ edata,
            int* __restrict__ row, float* __restrict__ dinv,
            uint4* __restrict__ tcnt) {
    __shared__ int2 sedata[BCAP];         // 80 KB sort staging
    __shared__ int loff[NBUCK * NTILE];   // counts -> offsets -> cursors
    __shared__ int tmp[512];
    int b = blockIdx.x, t = threadIdx.x;
    for (int i = t; i < NBUCK * NTILE; i += 512) loff[i] = 0;
    __syncthreads();
    int cnt = bucketCursor[b];
    int gb  = bucketBase[b];
    const int2* cb = coarse + (size_t)b * BCAP;
    int2 myE[RCAP]; int myKey[RCAP];
#pragma unroll
    for (int k = 0; k < RCAP; ++k) {
        int j = t + k * 512;               // coalesced
        if (j < cnt) {
            int2 e = cb[j];
            myE[k] = e;
            myKey[k] = (((e.x >> 18) & 511) << 3) | ((e.x & 0x3FFFF) >> TSH);
            atomicAdd(&loff[myKey[k]], 1);
        } else myKey[k] = -1;
    }
    __syncthreads();
    // exclusive scan over 4096 (thread t owns node t's 8 tile-bins)
    int base8 = t * 8, s = 0;
#pragma unroll
    for (int k = 0; k < 8; ++k) s += loff[base8 + k];
    tmp[t] = s;
    __syncthreads();
    for (int off = 1; off < 512; off <<= 1) {
        int v = (t >= off) ? tmp[t - off] : 0;
        __syncthreads();
        tmp[t] += v;
        __syncthreads();
    }
    int run = tmp[t] - s;
    int o[9];
#pragma unroll
    for (int k = 0; k < 8; ++k) { int v = loff[base8 + k]; o[k] = run; loff[base8 + k] = run; run += v; }
    o[8] = run;                            // end of node t's edge range
    __syncthreads();
    int node = b * 512 + t;
    row[node] = gb + o[0];
    uint4 p;
    p.x = (unsigned)(o[1] - o[0]) | ((unsigned)(o[2] - o[1]) << 16);
    p.y = (unsigned)(o[3] - o[2]) | ((unsigned)(o[4] - o[3]) << 16);
    p.z = (unsigned)(o[5] - o[4]) | ((unsigned)(o[6] - o[5]) << 16);
    p.w = (unsigned)(o[7] - o[6]) | ((unsigned)(o[8] - o[7]) << 16);
    tcnt[node] = p;
    // place into LDS staging (loff is the moving cursor)
#pragma unroll
    for (int k = 0; k < RCAP; ++k) {
        if (myKey[k] >= 0) {
            int pos = atomicAdd(&loff[myKey[k]], 1);
            sedata[pos] = make_int2(myE[k].x & 0x3FFFF, myE[k].y);
        }
    }
    __syncthreads();
    // coalesced streaming writeout
    for (int j = t; j < cnt; j += 512) edata[gb + j] = sedata[j];
    // deg = sum of ew over this node's LDS-resident run
    float dsum = 0.f;
    for (int j = o[0]; j < o[8]; ++j) dsum += __int_as_float(sedata[j].y);
    dinv[node] = rsqrtf(1.0f + dsum);      // +1 = self-loop weight
}

// --- pack: Xp[i] = (x0, x1, x2, dinv) -- the 16B aggA gather operand -----
__global__ void pack_kernel(const float* __restrict__ X, const float* __restrict__ dinv,
                            float4* __restrict__ Xp, int N) {
    int i = blockIdx.x * blockDim.x + threadIdx.x;
    if (i >= N) return;
    Xp[i] = make_float4(X[3 * i], X[3 * i + 1], X[3 * i + 2], dinv[i]);
}

// --- agg pass 1: tile-phased 16B-gather recompute, 4-deep batched; ------
// fused node2. 512 threads = 128 node-groups x 4 lanes; nodes (i, i+128).
__global__ __launch_bounds__(512) void
aggA_kernel(const int* __restrict__ row, const uint4* __restrict__ tcnt,
            const int2* __restrict__ edata, const float4* __restrict__ Xp,
            const float* __restrict__ W1, const float* __restrict__ b1,
            const float* __restrict__ W2, float* __restrict__ h2) {
    __shared__ float w1s[48];
    __shared__ float w[256];
    __shared__ float bb[16];
    __shared__ float sx[128][17];
    int t = threadIdx.x;
    if (t < 256) w[t] = W2[t];
    else if (t < 272) bb[t - 256] = b1[t - 256];
    else if (t >= 288 && t < 336) w1s[t - 288] = W1[t - 288];
    __syncthreads();
    int ln = t >> 2, l = t & 3;
    // my 4 output features' W1 columns (3 input rows)
    float w1r0[4], w1r1[4], w1r2[4];
#pragma unroll
    for (int c = 0; c < 4; ++c) {
        w1r0[c] = w1s[0 * 16 + 4 * l + c];
        w1r1[c] = w1s[1 * 16 + 4 * l + c];
        w1r2[c] = w1s[2 * 16 + 4 * l + c];
    }
    int iA = blockIdx.x * 256 + ln, iB = iA + 128;
    int eA = row[iA], eB = row[iB];
    uint4 cAv = tcnt[iA], cBv = tcnt[iB];
    unsigned ca[4] = {cAv.x, cAv.y, cAv.z, cAv.w};
    unsigned cb[4] = {cBv.x, cBv.y, cBv.z, cBv.w};
    float4 xpA = Xp[iA], xpB = Xp[iB];
    float diA = xpA.w, diB = xpB.w;
    float accA[4], accB[4];
#pragma unroll
    for (int c = 0; c < 4; ++c) {   // self-loop seed: h'_i = (X_i@W1)*dinv_i
        accA[c] = (xpA.x * w1r0[c] + xpA.y * w1r1[c] + xpA.z * w1r2[c]) * diA;
        accB[c] = (xpB.x * w1r0[c] + xpB.y * w1r1[c] + xpB.z * w1r2[c]) * diB;
    }
#pragma unroll
    for (int tt = 0; tt < NTILE; ++tt) {
        int nA = (ca[tt >> 1] >> ((tt & 1) * 16)) & 0xFFFF;
        int nB = (cb[tt >> 1] >> ((tt & 1) * 16)) & 0xFFFF;
        while (nA > 0) {                      // 4-deep batched gather
            int j1 = min(1, nA - 1), j2 = min(2, nA - 1), j3 = min(3, nA - 1);
            int2 e0 = nt_edge(edata + eA), e1 = nt_edge(edata + eA + j1),
                 e2 = nt_edge(edata + eA + j2), e3 = nt_edge(edata + eA + j3);
            float4 x0 = Xp[e0.x], x1 = Xp[e1.x], x2 = Xp[e2.x], x3 = Xp[e3.x];
            float g0 = __int_as_float(e0.y) * x0.w;
            float g1 = (nA > 1) ? __int_as_float(e1.y) * x1.w : 0.f;
            float g2 = (nA > 2) ? __int_as_float(e2.y) * x2.w : 0.f;
            float g3 = (nA > 3) ? __int_as_float(e3.y) * x3.w : 0.f;
            float s0 = x0.x * g0 + x1.x * g1 + x2.x * g2 + x3.x * g3;
            float s1 = x0.y * g0 + x1.y * g1 + x2.y * g2 + x3.y * g3;
            float s2 = x0.z * g0 + x1.z * g1 + x2.z * g2 + x3.z * g3;
#pragma unroll
            for (int c = 0; c < 4; ++c)
                accA[c] += s0 * w1r0[c] + s1 * w1r1[c] + s2 * w1r2[c];
            int m = min(nA, 4); eA += m; nA -= m;
        }
        while (nB > 0) {
            int j1 = min(1, nB - 1), j2 = min(2, nB - 1), j3 = min(3, nB - 1);
            int2 e0 = nt_edge(edata + eB), e1 = nt_edge(edata + eB + j1),
                 e2 = nt_edge(edata + eB + j2), e3 = nt_edge(edata + eB + j3);
            float4 x0 = Xp[e0.x], x1 = Xp[e1.x], x2 = Xp[e2.x], x3 = Xp[e3.x];
            float g0 = __int_as_float(e0.y) * x0.w;
            float g1 = (nB > 1) ? __int_as_float(e1.y) * x1.w : 0.f;
            float g2 = (nB > 2) ? __int_as_float(e2.y) * x2.w : 0.f;
            float g3 = (nB > 3) ? __int_as_float(e3.y) * x3.w : 0.f;
            float s0 = x0.x * g0 + x1.x * g1 + x2.x * g2 + x3.x * g3;
            float s1 = x0.y * g0 + x1.y * g1 + x2.y * g2 + x3.y * g3;
            float s2 = x0.z * g0 + x1.z * g1 + x2.z * g2 + x3.z * g3;
#pragma unroll
            for (int c = 0; c < 4; ++c)
                accB[c] += s0 * w1r0[c] + s1 * w1r1[c] + s2 * w1r2[c];
            int m = min(nB, 4); eB += m; nB -= m;
        }
        __syncthreads();
    }
    // fused node2: x = leaky(di*acc + b1); h2' = (x@W2)*di (LDS transpose)
    sx[ln][4 * l + 0] = leaky(diA * accA[0] + bb[4 * l + 0]);
    sx[ln][4 * l + 1] = leaky(diA * accA[1] + bb[4 * l + 1]);
    sx[ln][4 * l + 2] = leaky(diA * accA[2] + bb[4 * l + 2]);
    sx[ln][4 * l + 3] = leaky(diA * accA[3] + bb[4 * l + 3]);
    __syncthreads();
    {
        float a0 = 0.f, a1 = 0.f, a2 = 0.f, a3 = 0.f;
#pragma unroll
        for (int q = 0; q < 16; ++q) {
            float xv = sx[ln][q];
            a0 += xv * w[q * 16 + 4 * l + 0];
            a1 += xv * w[q * 16 + 4 * l + 1];
            a2 += xv * w[q * 16 + 4 * l + 2];
            a3 += xv * w[q * 16 + 4 * l + 3];
        }
        ((float4*)h2)[(size_t)iA * 4 + l] = make_float4(a0 * diA, a1 * diA, a2 * diA, a3 * diA);
    }
    __syncthreads();
    sx[ln][4 * l + 0] = leaky(diB * accB[0] + bb[4 * l + 0]);
    sx[ln][4 * l + 1] = leaky(diB * accB[1] + bb[4 * l + 1]);
    sx[ln][4 * l + 2] = leaky(diB * accB[2] + bb[4 * l + 2]);
    sx[ln][4 * l + 3] = leaky(diB * accB[3] + bb[4 * l + 3]);
    __syncthreads();
    {
        float a0 = 0.f, a1 = 0.f, a2 = 0.f, a3 = 0.f;
#pragma unroll
        for (int q = 0; q < 16; ++q) {
            float xv = sx[ln][q];
            a0 += xv * w[q * 16 + 4 * l + 0];
            a1 += xv * w[q * 16 + 4 * l + 1];
            a2 += xv * w[q * 16 + 4 * l + 2];
            a3 += xv * w[q * 16 + 4 * l + 3];
        }
        ((float4*)h2)[(size_t)iB * 4 + l] = make_float4(a0 * diB, a1 * diB, a2 * diB, a3 * diB);
    }
}

// --- agg pass 2, tile-phased 64B gather, 4-deep batched ------------------
__global__ __launch_bounds__(512) void
aggB_kernel(const int* __restrict__ row, const uint4* __restrict__ tcnt,
            const int2* __restrict__ edata, const float* __restrict__ dinv,
            const float* __restrict__ h2prime, float* __restrict__ agg2) {
    int t = threadIdx.x;
    int ln = t >> 2, l = t & 3;
    int iA = blockIdx.x * 256 + ln, iB = iA + 128;
    const float4* hp = (const float4*)h2prime;
    int eA = row[iA], eB = row[iB];
    uint4 cAv = tcnt[iA], cBv = tcnt[iB];
    unsigned ca[4] = {cAv.x, cAv.y, cAv.z, cAv.w};
    unsigned cb[4] = {cBv.x, cBv.y, cBv.z, cBv.w};
    float diA = dinv[iA], diB = dinv[iB];
    float4 accA = hp[(size_t)iA * 4 + l];    // self-loop seed (h2')
    float4 accB = hp[(size_t)iB * 4 + l];
#pragma unroll
    for (int tt = 0; tt < NTILE; ++tt) {
        int nA = (ca[tt >> 1] >> ((tt & 1) * 16)) & 0xFFFF;
        int nB = (cb[tt >> 1] >> ((tt & 1) * 16)) & 0xFFFF;
        while (nA > 0) {                      // 4-deep batched gather
            int j1 = min(1, nA - 1), j2 = min(2, nA - 1), j3 = min(3, nA - 1);
            int2 e0 = nt_edge(edata + eA), e1 = nt_edge(edata + eA + j1),
                 e2 = nt_edge(edata + eA + j2), e3 = nt_edge(edata + eA + j3);
            float4 v0 = hp[(size_t)e0.x * 4 + l], v1 = hp[(size_t)e1.x * 4 + l],
                   v2 = hp[(size_t)e2.x * 4 + l], v3 = hp[(size_t)e3.x * 4 + l];
            float w0 = __int_as_float(e0.y);
            float w1 = (nA > 1) ? __int_as_float(e1.y) : 0.f;
            float w2 = (nA > 2) ? __int_as_float(e2.y) : 0.f;
            float w3 = (nA > 3) ? __int_as_float(e3.y) : 0.f;
            accA.x += v0.x * w0 + v1.x * w1 + v2.x * w2 + v3.x * w3;
            accA.y += v0.y * w0 + v1.y * w1 + v2.y * w2 + v3.y * w3;
            accA.z += v0.z * w0 + v1.z * w1 + v2.z * w2 + v3.z * w3;
            accA.w += v0.w * w0 + v1.w * w1 + v2.w * w2 + v3.w * w3;
            int m = min(nA, 4); eA += m; nA -= m;
        }
        while (nB > 0) {
            int j1 = min(1, nB - 1), j2 = min(2, nB - 1), j3 = min(3, nB - 1);
            int2 e0 = nt_edge(edata + eB), e1 = nt_edge(edata + eB + j1),
                 e2 = nt_edge(edata + eB + j2), e3 = nt_edge(edata + eB + j3);
            float4 v0 = hp[(size_t)e0.x * 4 + l], v1 = hp[(size_t)e1.x * 4 + l],
                   v2 = hp[(size_t)e2.x * 4 + l], v3 = hp[(size_t)e3.x * 4 + l];
            float w0 = __int_as_float(e0.y);
            float w1 = (nB > 1) ? __int_as_float(e1.y) : 0.f;
            float w2 = (nB > 2) ? __int_as_float(e2.y) : 0.f;
            float w3 = (nB > 3) ? __int_as_float(e3.y) : 0.f;
            accB.x += v0.x * w0 + v1.x * w1 + v2.x * w2 + v3.x * w3;
            accB.y += v0.y * w0 + v1.y * w1 + v2.y * w2 + v3.y * w3;
            accB.z += v0.z * w0 + v1.z * w1 + v2.z * w2 + v3.z * w3;
            accB.w += v0.w * w0 + v1.w * w1 + v2.w * w2 + v3.w * w3;
            int m = min(nB, 4); eB += m; nB -= m;
        }
        __syncthreads();
    }
    nt_store4(accA.x * diA, accA.y * diA, accA.z * diA, accA.w * diA,
              agg2 + (size_t)iA * 16 + l * 4);
    nt_store4(accB.x * diB, accB.y * diB, accB.z * diB, accB.w * diB,
              agg2 + (size_t)iB * 16 + l * 4);
}

// --- tiny MLP head: 16 ->16 ->16 ->2 -------------------------------------
__device__ void head_mlp(const float* pooled,
                         const float* __restrict__ Wa, const float* __restrict__ ba,
                         const float* __restrict__ Wb, const float* __restrict__ bb,
                         const float* __restrict__ Wc, const float* __restrict__ bc,
                         float* o) {
    float t[16], u[16];
#pragma unroll
    for (int f = 0; f < 16; ++f) {
        float a = ba[f];
        for (int k = 0; k < 16; ++k) a += pooled[k] * Wa[k * 16 + f];
        t[f] = leaky(a);
    }
#pragma unroll
    for (int f = 0; f < 16; ++f) {
        float a = bb[f];
        for (int k = 0; k < 16; ++k) a += t[k] * Wb[k * 16 + f];
        u[f] = leaky(a);
    }
    float o0 = bc[0], o1 = bc[1];
    for (int k = 0; k < 16; ++k) { o0 += u[k] * Wc[2 * k]; o1 += u[k] * Wc[2 * k + 1]; }
    o[0] = o0; o[1] = o1;
}

// --- pool (block per graph; Batching sorted -> binary search) + heads ----
__global__ void pool_head_kernel(const float* __restrict__ agg2, const float* __restrict__ b2,
                                 const int* __restrict__ batching, int N,
                                 const float* __restrict__ Wp1, const float* __restrict__ bp1,
                                 const float* __restrict__ Wp2, const float* __restrict__ bp2,
                                 const float* __restrict__ Wp3, const float* __restrict__ bp3,
                                 const float* __restrict__ Wt1, const float* __restrict__ bt1,
                                 const float* __restrict__ Wt2, const float* __restrict__ bt2,
                                 const float* __restrict__ Wt3, const float* __restrict__ bt3,
                                 float* __restrict__ out) {
    int g = blockIdx.x;
    __shared__ int bounds[2];
    if (threadIdx.x < 2) {
        int v = g + (int)threadIdx.x;
        int lo = 0, hi = N;
        while (lo < hi) { int m = (lo + hi) >> 1; if (batching[m] < v) lo = m + 1; else hi = m; }
        bounds[threadIdx.x] = lo;
    }
    __syncthreads();
    int lo = bounds[0], hi = bounds[1];
    int f = threadIdx.x & 15, r = threadIdx.x >> 4;    // 16 rows x 16 features
    float bf = b2[f];
    float acc = 0.f;
    for (int i = lo + r; i < hi; i += 16) acc += leaky(agg2[(size_t)i * 16 + f] + bf);
    __shared__ float red[16][17];
    red[r][f] = acc;
    __syncthreads();
    __shared__ float pooled[16];
    if (r == 0) {
        float s = 0.f;
#pragma unroll
        for (int k = 0; k < 16; ++k) s += red[k][f];
        pooled[f] = s / fmaxf((float)(hi - lo), 1.0f);
    }
    __syncthreads();
    if (threadIdx.x == 0) {
        float o[2];
        head_mlp(pooled, Wp1, bp1, Wp2, bp2, Wp3, bp3, o);
        out[4 * g + 0] = o[0]; out[4 * g + 1] = o[1];
    } else if (threadIdx.x == 1) {
        float o[2];
        head_mlp(pooled, Wt1, bt1, Wt2, bt2, Wt3, bt3, o);
        out[4 * g + 2] = o[0]; out[4 * g + 3] = o[1];
    }
}

extern "C" void kernel_launch(void* const* d_in, const int* in_sizes, int n_in,
                              void* d_out, int out_size, void* d_ws, size_t ws_size,
                              hipStream_t stream) {
    const float* X        = (const float*)d_in[0];
    const int*   ei       = (const int*)d_in[1];
    const float* ew       = (const float*)d_in[2];
    const int*   batching = (const int*)d_in[3];
    const float* W1  = (const float*)d_in[5];  const float* b1  = (const float*)d_in[6];
    const float* W2  = (const float*)d_in[7];  const float* b2  = (const float*)d_in[8];
    const float* Wp1 = (const float*)d_in[9];  const float* bp1 = (const float*)d_in[10];
    const float* Wp2 = (const float*)d_in[11]; const float* bp2 = (const float*)d_in[12];
    const float* Wp3 = (const float*)d_in[13]; const float* bp3 = (const float*)d_in[14];
    const float* Wt1 = (const float*)d_in[15]; const float* bt1 = (const float*)d_in[16];
    const float* Wt2 = (const float*)d_in[17]; const float* bt2 = (const float*)d_in[18];
    const float* Wt3 = (const float*)d_in[19]; const float* bt3 = (const float*)d_in[20];

    const int N = in_sizes[3];        // 262144 = 512 * 512
    const int E = in_sizes[2];        // 4194304
    const int G = out_size / 4;       // 1024
    const int* src = ei;
    const int* dst = ei + E;

    char* ws = (char*)d_ws;
    size_t off = 0;
    int2*  edata = (int2*)(ws + off);  off += (size_t)E * 8;              // 32 MB fine CSR
    char*  regionA = ws + off;         off += (size_t)N * 64 * 3;         // 48 MB
    // regionA phase 1: coarse buckets (40 MB); phase 2: h2' | agg2 | Xp
    // (pack/aggA run only after binB has consumed coarse)
    int2*  coarse = (int2*)regionA;
    float* h2     = (float*)regionA;
    float* agg2   = (float*)(regionA + (size_t)N * 64);
    float4* Xp    = (float4*)(regionA + (size_t)N * 128);                 // 4 MB
    int*   bucketCursor = (int*)(ws + off); off += NBUCK * 4;
    int*   bucketBase   = (int*)(ws + off); off += NBUCK * 4;
    int*   row   = (int*)(ws + off);   off += (size_t)(N + 4) * 4;
    float* dinv  = (float*)(ws + off); off += (size_t)N * 4;
    uint4* tcnt  = (uint4*)(ws + off); off += (size_t)N * 16;             // 4 MB
    float* out   = (float*)d_out;

    hipMemsetAsync(bucketCursor, 0, NBUCK * 4, stream);

    const int tb = 256;
    binA_kernel<<<(E + CHUNK - 1) / CHUNK, 512, 0, stream>>>(src, dst, ew, bucketCursor, coarse, E);
    bscan_kernel<<<1, NBUCK, 0, stream>>>(bucketCursor, bucketBase, row, N, E);
    binB_kernel<<<NBUCK, 512, 0, stream>>>(bucketCursor, bucketBase, coarse, edata, row, dinv, tcnt);
    pack_kernel<<<(N + tb - 1) / tb, tb, 0, stream>>>(X, dinv, Xp, N);
    aggA_kernel<<<N / 256, 512, 0, stream>>>(row, tcnt, edata, Xp, W1, b1, W2, h2);
    aggB_kernel<<<N / 256, 512, 0, stream>>>(row, tcnt, edata, dinv, h2, agg2);
    pool_head_kernel<<<G, tb, 0, stream>>>(agg2, b2, batching, N,
                                           Wp1, bp1, Wp2, bp2, Wp3, bp3,
                                           Wt1, bt1, Wt2, bt2, Wt3, bt3, out);
}

// Round 11
// 396.620 us; speedup vs baseline: 1.0824x; 1.0824x over previous
//
#include <hip/hip_runtime.h>

// GCN: 2x GCNConv(sym-norm, self-loops) + mean-pool + 2 MLP heads.
// R13: tile-major edata + LDS edge streaming in the agg kernels.
// binB sorts each bucket by (tile,node) so a bucket-tile is ONE contiguous
// edata segment; agg phases cooperatively load their half-segment into LDS
// (coalesced) and walk runs from LDS -> the per-edge dependent chain loses
// its edata L2 pointer-chase (ds_read ~30cy vs ~200cy) and edata request
// pressure drops ~64x. Metadata: tstart[b][9] (abs tile starts), ntoff
// (8xu16 within-tile node offsets), tcnt (8xu16 counts).
// NT hints: NONE (R6: NT-store on gathered array toxic; R10: NT-load
// bypasses L1/L2 allocation -> latency disaster). Carried: tile-phased
// lockstep sweep (R4/R5), 16B Xp operand in aggA (R7), LDS sorts +
// coalesced writeout (R3/R4), no float LDS atomics (R2), sequential A/B
// loops (R8), binA CHUNK=8192 (R7).

#define NBUCK 512          // coarse buckets = dst >> 9
#define BCAP  10240        // slack capacity per bucket (mean 8192, sigma ~90)
#define CHUNK 8192         // edges per pass-A block (16 per bucket avg)
#define APT   16           // edges per thread in binA (CHUNK/512)
#define NTILE 8            // src tiles = src >> 15
#define TSH   15
#define RCAP  20           // BCAP/512 register-staged edges per thread
#define SEGCAP 1024        // LDS cap for a half-bucket tile segment (mean 512)

__device__ __forceinline__ float leaky(float x) { return x > 0.f ? x : 0.01f * x; }

// --- Pass A: bin edges by dst>>9 into slack-capacity coarse buckets ------
__global__ __launch_bounds__(512) void
binA_kernel(const int* __restrict__ src, const int* __restrict__ dst,
            const float* __restrict__ ew, int* __restrict__ bucketCursor,
            int2* __restrict__ coarse, int E) {
    __shared__ int lhist[NBUCK], lbase[NBUCK], lcur[NBUCK], gbase[NBUCK];
    __shared__ int tmp[NBUCK];
    __shared__ int2 stag[CHUNK];              // 64 KB
    __shared__ unsigned short sbuck[CHUNK];   // 16 KB
    int t = threadIdx.x;
    int base = blockIdx.x * CHUNK;
    lhist[t] = 0; lcur[t] = 0;
    __syncthreads();
    int n = min(CHUNK, E - base);
    int myDst[APT], mySrc[APT]; float myEw[APT];
#pragma unroll
    for (int k = 0; k < APT; ++k) {
        int j = t + k * 512;                  // coalesced
        if (j < n) {
            int d = dst[base + j];
            myDst[k] = d; mySrc[k] = src[base + j]; myEw[k] = ew[base + j];
            atomicAdd(&lhist[d >> 9], 1);
        } else myDst[k] = -1;
    }
    __syncthreads();
    // exclusive scan of lhist (512 entries, 512 threads)
    int hv = lhist[t];
    tmp[t] = hv;
    __syncthreads();
    for (int off = 1; off < NBUCK; off <<= 1) {
        int v = (t >= off) ? tmp[t - off] : 0;
        __syncthreads();
        tmp[t] += v;
        __syncthreads();
    }
    lbase[t] = tmp[t] - hv;
    gbase[t] = hv ? atomicAdd(&bucketCursor[t], hv) : 0;
    __syncthreads();
    // stage into LDS, sorted by bucket; pack (src | ldst<<18, ew)
#pragma unroll
    for (int k = 0; k < APT; ++k) {
        int d = myDst[k];
        if (d >= 0) {
            int b = d >> 9;
            int p = lbase[b] + atomicAdd(&lcur[b], 1);
            stag[p] = make_int2(mySrc[k] | ((d & 511) << 18), __float_as_int(myEw[k]));
            sbuck[p] = (unsigned short)b;
        }
    }
    __syncthreads();
    // write out: consecutive j -> consecutive addresses within bucket runs
    for (int j = t; j < n; j += 512) {
        int b = sbuck[j];
        coarse[(size_t)b * BCAP + gbase[b] + (j - lbase[b])] = stag[j];
    }
}

// --- scan bucket counts -> bucket bases (1 block x 512) ------------------
__global__ void bscan_kernel(const int* __restrict__ bucketCursor,
                             int* __restrict__ bucketBase) {
    __shared__ int s[NBUCK];
    int t = threadIdx.x;
    int v = bucketCursor[t];
    s[t] = v;
    __syncthreads();
    for (int off = 1; off < NBUCK; off <<= 1) {
        int x = (t >= off) ? s[t - off] : 0;
        __syncthreads();
        s[t] += x;
        __syncthreads();
    }
    bucketBase[t] = s[t] - v;
}

// --- Pass B: LDS-staged TILE-MAJOR counting sort; coalesced writeout -----
// key = (tile<<9)|ld -> bucket-tile segments are contiguous in edata.
// Emits tstartAbs[b][9], ntoff (within-tile offsets), tcnt (counts), dinv.
__global__ __launch_bounds__(512, 2) void
binB_kernel(const int* __restrict__ bucketCursor, const int* __restrict__ bucketBase,
            const int2* __restrict__ coarse, int2* __restrict__ edata,
            float* __restrict__ dinv, uint4* __restrict__ tcnt,
            uint4* __restrict__ ntoff, int* __restrict__ tstartAbs) {
    __shared__ int2 sedata[BCAP];         // 80 KB sort staging
    __shared__ int loff[NBUCK * NTILE];   // counts -> offsets -> cursors
    __shared__ int tmp[512];
    __shared__ int tbase[NTILE + 1];
    int b = blockIdx.x, t = threadIdx.x;
    for (int i = t; i < NBUCK * NTILE; i += 512) loff[i] = 0;
    __syncthreads();
    int cnt = bucketCursor[b];
    int gb  = bucketBase[b];
    const int2* cb = coarse + (size_t)b * BCAP;
    int2 myE[RCAP]; int myKey[RCAP];
#pragma unroll
    for (int k = 0; k < RCAP; ++k) {
        int j = t + k * 512;               // coalesced
        if (j < cnt) {
            int2 e = cb[j];
            myE[k] = e;
            int sv = e.x & 0x3FFFF;
            myKey[k] = ((sv >> TSH) << 9) | ((e.x >> 18) & 511);
            atomicAdd(&loff[myKey[k]], 1);
        } else myKey[k] = -1;
    }
    __syncthreads();
    // exclusive scan over 4096 linear (thread t owns [8t, 8t+8))
    int base8 = t * 8, s = 0;
#pragma unroll
    for (int k = 0; k < 8; ++k) s += loff[base8 + k];
    tmp[t] = s;
    __syncthreads();
    for (int off = 1; off < 512; off <<= 1) {
        int v = (t >= off) ? tmp[t - off] : 0;
        __syncthreads();
        tmp[t] += v;
        __syncthreads();
    }
    int run = tmp[t] - s;
#pragma unroll
    for (int k = 0; k < 8; ++k) { int v = loff[base8 + k]; loff[base8 + k] = run; run += v; }
    __syncthreads();
    // tile bases within bucket
    if (t < 8) tbase[t] = loff[t * 512];
    if (t == 0) tbase[8] = cnt;
    __syncthreads();
    // per-node metadata: node = ld = t; key (tt, t) at loff[tt*512 + t]
    int o[8], c[8];
#pragma unroll
    for (int tt = 0; tt < 8; ++tt) {
        int cur = loff[tt * 512 + t];
        int nxt = (t < 511) ? loff[tt * 512 + t + 1] : tbase[tt + 1];
        o[tt] = cur - tbase[tt];
        c[tt] = nxt - cur;
    }
    int node = b * 512 + t;
    uint4 p, q;
    p.x = (unsigned)c[0] | ((unsigned)c[1] << 16);
    p.y = (unsigned)c[2] | ((unsigned)c[3] << 16);
    p.z = (unsigned)c[4] | ((unsigned)c[5] << 16);
    p.w = (unsigned)c[6] | ((unsigned)c[7] << 16);
    tcnt[node] = p;
    q.x = (unsigned)o[0] | ((unsigned)o[1] << 16);
    q.y = (unsigned)o[2] | ((unsigned)o[3] << 16);
    q.z = (unsigned)o[4] | ((unsigned)o[5] << 16);
    q.w = (unsigned)o[6] | ((unsigned)o[7] << 16);
    ntoff[node] = q;
    if (t < 9) tstartAbs[b * 9 + t] = gb + tbase[t];
    __syncthreads();   // captures done before cursors move
    // placement into LDS staging (loff is the moving cursor)
#pragma unroll
    for (int k = 0; k < RCAP; ++k) {
        if (myKey[k] >= 0) {
            int pos = atomicAdd(&loff[myKey[k]], 1);
            sedata[pos] = make_int2(myE[k].x & 0x3FFFF, myE[k].y);
        }
    }
    __syncthreads();
    // coalesced streaming writeout
    for (int j = t; j < cnt; j += 512) edata[gb + j] = sedata[j];
    // deg = sum of ew over this node's 8 LDS-resident segments
    float dsum = 0.f;
#pragma unroll
    for (int tt = 0; tt < 8; ++tt) {
        int s0 = tbase[tt] + o[tt];
        for (int k = 0; k < c[tt]; ++k) dsum += __int_as_float(sedata[s0 + k].y);
    }
    dinv[node] = rsqrtf(1.0f + dsum);      // +1 = self-loop weight
}

// --- pack: Xp[i] = (x0, x1, x2, dinv) -- the 16B aggA gather operand -----
__global__ void pack_kernel(const float* __restrict__ X, const float* __restrict__ dinv,
                            float4* __restrict__ Xp, int N) {
    int i = blockIdx.x * blockDim.x + threadIdx.x;
    if (i >= N) return;
    Xp[i] = make_float4(X[3 * i], X[3 * i + 1], X[3 * i + 2], dinv[i]);
}

// --- agg pass 1: tile-phased, LDS edge stream, 16B Xp recompute; --------
// fused node2. Block = half a bucket (256 nodes); per phase the half-
// segment is loaded coalesced into LDS, runs consumed from LDS.
__global__ __launch_bounds__(512) void
aggA_kernel(const int* __restrict__ tstartAbs, const uint4* __restrict__ tcnt,
            const uint4* __restrict__ ntoff, const int2* __restrict__ edata,
            const float4* __restrict__ Xp, const float* __restrict__ W1,
            const float* __restrict__ b1, const float* __restrict__ W2,
            float* __restrict__ h2) {
    __shared__ int2 sedge[SEGCAP];        // 8 KB edge stream
    __shared__ float w1s[48];
    __shared__ float w[256];
    __shared__ float bb[16];
    __shared__ float sx[128][17];
    int t = threadIdx.x;
    if (t < 256) w[t] = W2[t];
    else if (t < 272) bb[t - 256] = b1[t - 256];
    else if (t >= 288 && t < 336) w1s[t - 288] = W1[t - 288];
    __syncthreads();
    int ln = t >> 2, l = t & 3;
    float w1r0[4], w1r1[4], w1r2[4];
#pragma unroll
    for (int c = 0; c < 4; ++c) {
        w1r0[c] = w1s[0 * 16 + 4 * l + c];
        w1r1[c] = w1s[1 * 16 + 4 * l + c];
        w1r2[c] = w1s[2 * 16 + 4 * l + c];
    }
    int bk = blockIdx.x >> 1, half = blockIdx.x & 1;
    int iA = blockIdx.x * 256 + ln, iB = iA + 128;
    int tsr[9];
#pragma unroll
    for (int k = 0; k < 9; ++k) tsr[k] = tstartAbs[bk * 9 + k];
    uint4 cAv = tcnt[iA], cBv = tcnt[iB];
    uint4 oAv = ntoff[iA], oBv = ntoff[iB];
    uint4 mV  = ntoff[bk * 512 + 256];    // midRel per tile
    unsigned ca[4] = {cAv.x, cAv.y, cAv.z, cAv.w};
    unsigned cbv[4] = {cBv.x, cBv.y, cBv.z, cBv.w};
    unsigned oa[4] = {oAv.x, oAv.y, oAv.z, oAv.w};
    unsigned ob[4] = {oBv.x, oBv.y, oBv.z, oBv.w};
    unsigned mr[4] = {mV.x, mV.y, mV.z, mV.w};
    float4 xpA = Xp[iA], xpB = Xp[iB];
    float diA = xpA.w, diB = xpB.w;
    float accA[4], accB[4];
#pragma unroll
    for (int c = 0; c < 4; ++c) {   // self-loop seed: h'_i = (X_i@W1)*dinv_i
        accA[c] = (xpA.x * w1r0[c] + xpA.y * w1r1[c] + xpA.z * w1r2[c]) * diA;
        accB[c] = (xpB.x * w1r0[c] + xpB.y * w1r1[c] + xpB.z * w1r2[c]) * diB;
    }
#pragma unroll
    for (int tt = 0; tt < NTILE; ++tt) {
        int midRel = (mr[tt >> 1] >> ((tt & 1) * 16)) & 0xFFFF;
        int segBase = tsr[tt];
        int ls = segBase + (half ? midRel : 0);
        int le = half ? tsr[tt + 1] : segBase + midRel;
        for (int j = ls + t; j < le; j += 512) sedge[j - ls] = edata[j];
        __syncthreads();
        int rel = half ? midRel : 0;
        int sA = (int)((oa[tt >> 1] >> ((tt & 1) * 16)) & 0xFFFF) - rel;
        int nA = (ca[tt >> 1] >> ((tt & 1) * 16)) & 0xFFFF;
        for (int k = 0; k < nA; ++k) {
            int2 e = sedge[sA + k];
            float4 xs = Xp[e.x];
            float f = __int_as_float(e.y) * xs.w;
            float f0 = xs.x * f, f1 = xs.y * f, f2 = xs.z * f;
#pragma unroll
            for (int c = 0; c < 4; ++c)
                accA[c] += f0 * w1r0[c] + f1 * w1r1[c] + f2 * w1r2[c];
        }
        int sB = (int)((ob[tt >> 1] >> ((tt & 1) * 16)) & 0xFFFF) - rel;
        int nB = (cbv[tt >> 1] >> ((tt & 1) * 16)) & 0xFFFF;
        for (int k = 0; k < nB; ++k) {
            int2 e = sedge[sB + k];
            float4 xs = Xp[e.x];
            float f = __int_as_float(e.y) * xs.w;
            float f0 = xs.x * f, f1 = xs.y * f, f2 = xs.z * f;
#pragma unroll
            for (int c = 0; c < 4; ++c)
                accB[c] += f0 * w1r0[c] + f1 * w1r1[c] + f2 * w1r2[c];
        }
        __syncthreads();
    }
    // fused node2: x = leaky(di*acc + b1); h2' = (x@W2)*di (LDS transpose)
    sx[ln][4 * l + 0] = leaky(diA * accA[0] + bb[4 * l + 0]);
    sx[ln][4 * l + 1] = leaky(diA * accA[1] + bb[4 * l + 1]);
    sx[ln][4 * l + 2] = leaky(diA * accA[2] + bb[4 * l + 2]);
    sx[ln][4 * l + 3] = leaky(diA * accA[3] + bb[4 * l + 3]);
    __syncthreads();
    {
        float a0 = 0.f, a1 = 0.f, a2 = 0.f, a3 = 0.f;
#pragma unroll
        for (int q = 0; q < 16; ++q) {
            float xv = sx[ln][q];
            a0 += xv * w[q * 16 + 4 * l + 0];
            a1 += xv * w[q * 16 + 4 * l + 1];
            a2 += xv * w[q * 16 + 4 * l + 2];
            a3 += xv * w[q * 16 + 4 * l + 3];
        }
        ((float4*)h2)[(size_t)iA * 4 + l] = make_float4(a0 * diA, a1 * diA, a2 * diA, a3 * diA);
    }
    __syncthreads();
    sx[ln][4 * l + 0] = leaky(diB * accB[0] + bb[4 * l + 0]);
    sx[ln][4 * l + 1] = leaky(diB * accB[1] + bb[4 * l + 1]);
    sx[ln][4 * l + 2] = leaky(diB * accB[2] + bb[4 * l + 2]);
    sx[ln][4 * l + 3] = leaky(diB * accB[3] + bb[4 * l + 3]);
    __syncthreads();
    {
        float a0 = 0.f, a1 = 0.f, a2 = 0.f, a3 = 0.f;
#pragma unroll
        for (int q = 0; q < 16; ++q) {
            float xv = sx[ln][q];
            a0 += xv * w[q * 16 + 4 * l + 0];
            a1 += xv * w[q * 16 + 4 * l + 1];
            a2 += xv * w[q * 16 + 4 * l + 2];
            a3 += xv * w[q * 16 + 4 * l + 3];
        }
        ((float4*)h2)[(size_t)iB * 4 + l] = make_float4(a0 * diB, a1 * diB, a2 * diB, a3 * diB);
    }
}

// --- agg pass 2: tile-phased 64B gather, LDS edge stream -----------------
__global__ __launch_bounds__(512) void
aggB_kernel(const int* __restrict__ tstartAbs, const uint4* __restrict__ tcnt,
            const uint4* __restrict__ ntoff, const int2* __restrict__ edata,
            const float* __restrict__ dinv, const float* __restrict__ h2prime,
            float* __restrict__ agg2) {
    __shared__ int2 sedge[SEGCAP];        // 8 KB edge stream
    int t = threadIdx.x;
    int ln = t >> 2, l = t & 3;
    int bk = blockIdx.x >> 1, half = blockIdx.x & 1;
    int iA = blockIdx.x * 256 + ln, iB = iA + 128;
    const float4* hp = (const float4*)h2prime;
    int tsr[9];
#pragma unroll
    for (int k = 0; k < 9; ++k) tsr[k] = tstartAbs[bk * 9 + k];
    uint4 cAv = tcnt[iA], cBv = tcnt[iB];
    uint4 oAv = ntoff[iA], oBv = ntoff[iB];
    uint4 mV  = ntoff[bk * 512 + 256];
    unsigned ca[4] = {cAv.x, cAv.y, cAv.z, cAv.w};
    unsigned cbv[4] = {cBv.x, cBv.y, cBv.z, cBv.w};
    unsigned oa[4] = {oAv.x, oAv.y, oAv.z, oAv.w};
    unsigned ob[4] = {oBv.x, oBv.y, oBv.z, oBv.w};
    unsigned mr[4] = {mV.x, mV.y, mV.z, mV.w};
    float diA = dinv[iA], diB = dinv[iB];
    float4 accA = hp[(size_t)iA * 4 + l];    // self-loop seed (h2')
    float4 accB = hp[(size_t)iB * 4 + l];
#pragma unroll
    for (int tt = 0; tt < NTILE; ++tt) {
        int midRel = (mr[tt >> 1] >> ((tt & 1) * 16)) & 0xFFFF;
        int segBase = tsr[tt];
        int ls = segBase + (half ? midRel : 0);
        int le = half ? tsr[tt + 1] : segBase + midRel;
        for (int j = ls + t; j < le; j += 512) sedge[j - ls] = edata[j];
        __syncthreads();
        int rel = half ? midRel : 0;
        int sA = (int)((oa[tt >> 1] >> ((tt & 1) * 16)) & 0xFFFF) - rel;
        int nA = (ca[tt >> 1] >> ((tt & 1) * 16)) & 0xFFFF;
        for (int k = 0; k < nA; ++k) {
            int2 e = sedge[sA + k];
            float ewv = __int_as_float(e.y);
            float4 v = hp[(size_t)e.x * 4 + l];
            accA.x += v.x * ewv; accA.y += v.y * ewv;
            accA.z += v.z * ewv; accA.w += v.w * ewv;
        }
        int sB = (int)((ob[tt >> 1] >> ((tt & 1) * 16)) & 0xFFFF) - rel;
        int nB = (cbv[tt >> 1] >> ((tt & 1) * 16)) & 0xFFFF;
        for (int k = 0; k < nB; ++k) {
            int2 e = sedge[sB + k];
            float ewv = __int_as_float(e.y);
            float4 v = hp[(size_t)e.x * 4 + l];
            accB.x += v.x * ewv; accB.y += v.y * ewv;
            accB.z += v.z * ewv; accB.w += v.w * ewv;
        }
        __syncthreads();
    }
    ((float4*)agg2)[(size_t)iA * 4 + l] =
        make_float4(accA.x * diA, accA.y * diA, accA.z * diA, accA.w * diA);
    ((float4*)agg2)[(size_t)iB * 4 + l] =
        make_float4(accB.x * diB, accB.y * diB, accB.z * diB, accB.w * diB);
}

// --- tiny MLP head: 16 ->16 ->16 ->2 -------------------------------------
__device__ void head_mlp(const float* pooled,
                         const float* __restrict__ Wa, const float* __restrict__ ba,
                         const float* __restrict__ Wb, const float* __restrict__ bb,
                         const float* __restrict__ Wc, const float* __restrict__ bc,
                         float* o) {
    float t[16], u[16];
#pragma unroll
    for (int f = 0; f < 16; ++f) {
        float a = ba[f];
        for (int k = 0; k < 16; ++k) a += pooled[k] * Wa[k * 16 + f];
        t[f] = leaky(a);
    }
#pragma unroll
    for (int f = 0; f < 16; ++f) {
        float a = bb[f];
        for (int k = 0; k < 16; ++k) a += t[k] * Wb[k * 16 + f];
        u[f] = leaky(a);
    }
    float o0 = bc[0], o1 = bc[1];
    for (int k = 0; k < 16; ++k) { o0 += u[k] * Wc[2 * k]; o1 += u[k] * Wc[2 * k + 1]; }
    o[0] = o0; o[1] = o1;
}

// --- pool (block per graph; Batching sorted -> binary search) + heads ----
__global__ void pool_head_kernel(const float* __restrict__ agg2, const float* __restrict__ b2,
                                 const int* __restrict__ batching, int N,
                                 const float* __restrict__ Wp1, const float* __restrict__ bp1,
                                 const float* __restrict__ Wp2, const float* __restrict__ bp2,
                                 const float* __restrict__ Wp3, const float* __restrict__ bp3,
                                 const float* __restrict__ Wt1, const float* __restrict__ bt1,
                                 const float* __restrict__ Wt2, const float* __restrict__ bt2,
                                 const float* __restrict__ Wt3, const float* __restrict__ bt3,
                                 float* __restrict__ out) {
    int g = blockIdx.x;
    __shared__ int bounds[2];
    if (threadIdx.x < 2) {
        int v = g + (int)threadIdx.x;
        int lo = 0, hi = N;
        while (lo < hi) { int m = (lo + hi) >> 1; if (batching[m] < v) lo = m + 1; else hi = m; }
        bounds[threadIdx.x] = lo;
    }
    __syncthreads();
    int lo = bounds[0], hi = bounds[1];
    int f = threadIdx.x & 15, r = threadIdx.x >> 4;    // 16 rows x 16 features
    float bf = b2[f];
    float acc = 0.f;
    for (int i = lo + r; i < hi; i += 16) acc += leaky(agg2[(size_t)i * 16 + f] + bf);
    __shared__ float red[16][17];
    red[r][f] = acc;
    __syncthreads();
    __shared__ float pooled[16];
    if (r == 0) {
        float s = 0.f;
#pragma unroll
        for (int k = 0; k < 16; ++k) s += red[k][f];
        pooled[f] = s / fmaxf((float)(hi - lo), 1.0f);
    }
    __syncthreads();
    if (threadIdx.x == 0) {
        float o[2];
        head_mlp(pooled, Wp1, bp1, Wp2, bp2, Wp3, bp3, o);
        out[4 * g + 0] = o[0]; out[4 * g + 1] = o[1];
    } else if (threadIdx.x == 1) {
        float o[2];
        head_mlp(pooled, Wt1, bt1, Wt2, bt2, Wt3, bt3, o);
        out[4 * g + 2] = o[0]; out[4 * g + 3] = o[1];
    }
}

extern "C" void kernel_launch(void* const* d_in, const int* in_sizes, int n_in,
                              void* d_out, int out_size, void* d_ws, size_t ws_size,
                              hipStream_t stream) {
    const float* X        = (const float*)d_in[0];
    const int*   ei       = (const int*)d_in[1];
    const float* ew       = (const float*)d_in[2];
    const int*   batching = (const int*)d_in[3];
    const float* W1  = (const float*)d_in[5];  const float* b1  = (const float*)d_in[6];
    const float* W2  = (const float*)d_in[7];  const float* b2  = (const float*)d_in[8];
    const float* Wp1 = (const float*)d_in[9];  const float* bp1 = (const float*)d_in[10];
    const float* Wp2 = (const float*)d_in[11]; const float* bp2 = (const float*)d_in[12];
    const float* Wp3 = (const float*)d_in[13]; const float* bp3 = (const float*)d_in[14];
    const float* Wt1 = (const float*)d_in[15]; const float* bt1 = (const float*)d_in[16];
    const float* Wt2 = (const float*)d_in[17]; const float* bt2 = (const float*)d_in[18];
    const float* Wt3 = (const float*)d_in[19]; const float* bt3 = (const float*)d_in[20];

    const int N = in_sizes[3];        // 262144 = 512 * 512
    const int E = in_sizes[2];        // 4194304
    const int G = out_size / 4;       // 1024
    const int* src = ei;
    const int* dst = ei + E;

    char* ws = (char*)d_ws;
    size_t off = 0;
    int2*  edata = (int2*)(ws + off);  off += (size_t)E * 8;              // 32 MB fine CSR
    char*  regionA = ws + off;         off += (size_t)N * 64 * 3;         // 48 MB
    // regionA phase 1: coarse buckets (40 MB); phase 2: h2' | agg2 | Xp
    // (pack/aggA run only after binB has consumed coarse)
    int2*  coarse = (int2*)regionA;
    float* h2     = (float*)regionA;
    float* agg2   = (float*)(regionA + (size_t)N * 64);
    float4* Xp    = (float4*)(regionA + (size_t)N * 128);                 // 4 MB
    int*   bucketCursor = (int*)(ws + off); off += NBUCK * 4;
    int*   bucketBase   = (int*)(ws + off); off += NBUCK * 4;
    float* dinv  = (float*)(ws + off); off += (size_t)N * 4;
    uint4* tcnt  = (uint4*)(ws + off); off += (size_t)N * 16;             // 4 MB
    uint4* ntoff = (uint4*)(ws + off); off += (size_t)N * 16;             // 4 MB
    int*   tstartAbs = (int*)(ws + off); off += (size_t)NBUCK * 9 * 4;
    float* out   = (float*)d_out;

    hipMemsetAsync(bucketCursor, 0, NBUCK * 4, stream);

    const int tb = 256;
    binA_kernel<<<(E + CHUNK - 1) / CHUNK, 512, 0, stream>>>(src, dst, ew, bucketCursor, coarse, E);
    bscan_kernel<<<1, NBUCK, 0, stream>>>(bucketCursor, bucketBase);
    binB_kernel<<<NBUCK, 512, 0, stream>>>(bucketCursor, bucketBase, coarse, edata,
                                           dinv, tcnt, ntoff, tstartAbs);
    pack_kernel<<<(N + tb - 1) / tb, tb, 0, stream>>>(X, dinv, Xp, N);
    aggA_kernel<<<N / 256, 512, 0, stream>>>(tstartAbs, tcnt, ntoff, edata, Xp, W1, b1, W2, h2);
    aggB_kernel<<<N / 256, 512, 0, stream>>>(tstartAbs, tcnt, ntoff, edata, dinv, h2, agg2);
    pool_head_kernel<<<G, tb, 0, stream>>>(agg2, b2, batching, N,
                                           Wp1, bp1, Wp2, bp2, Wp3, bp3,
                                           Wt1, bt1, Wt2, bt2, Wt3, bt3, out);
}

// Round 12
// 388.552 us; speedup vs baseline: 1.1049x; 1.0208x over previous
//
#include <hip/hip_runtime.h>

// GCN: 2x GCNConv(sym-norm, self-loops) + mean-pool + 2 MLP heads.
// R14: R7 (348us best) + the ONE proven-positive lever from R8-R11
// (R9's 4-deep batched gathers, BW 2.8->3.6TB/s) + NTILE 8->16 so the
// per-phase gather window (1MB h2 / 0.25MB Xp) leaves L2 headroom for
// batch-4's request rate (R9's only cost was +71MB window re-fetch).
// Run lengths/tile ~Poisson(1) -> one super-iteration covers most runs.
// NO NT hints (R6: NT-store on gathered array toxic; R10: NT-load skips
// L2 allocation). NO LDS edge staging (R11: serializes load vs gather).
// NO A/B interleave (R8: exec-masked double body). Carried: tile-phased
// lockstep sweep (R4/R5), 16B Xp operand (R7), LDS sorts + coalesced
// writeout (R3/R4), no float LDS atomics (R2), binA CHUNK=8192 (R7).

#define NBUCK 512          // coarse buckets = dst >> 9
#define BCAP  10240        // slack capacity per bucket (mean 8192, sigma ~90)
#define CHUNK 8192         // edges per pass-A block (16 per bucket avg)
#define APT   16           // edges per thread in binA (CHUNK/512)
#define NTILE 16           // src tiles = src >> 14 (0.25MB Xp / 1MB h2 per tile)
#define TSH   14
#define RCAP  20           // BCAP/512 register-staged edges per thread

__device__ __forceinline__ float leaky(float x) { return x > 0.f ? x : 0.01f * x; }

// --- Pass A: bin edges by dst>>9 into slack-capacity coarse buckets ------
__global__ __launch_bounds__(512) void
binA_kernel(const int* __restrict__ src, const int* __restrict__ dst,
            const float* __restrict__ ew, int* __restrict__ bucketCursor,
            int2* __restrict__ coarse, int E) {
    __shared__ int lhist[NBUCK], lbase[NBUCK], lcur[NBUCK], gbase[NBUCK];
    __shared__ int tmp[NBUCK];
    __shared__ int2 stag[CHUNK];              // 64 KB
    __shared__ unsigned short sbuck[CHUNK];   // 16 KB
    int t = threadIdx.x;
    int base = blockIdx.x * CHUNK;
    lhist[t] = 0; lcur[t] = 0;
    __syncthreads();
    int n = min(CHUNK, E - base);
    int myDst[APT], mySrc[APT]; float myEw[APT];
#pragma unroll
    for (int k = 0; k < APT; ++k) {
        int j = t + k * 512;                  // coalesced
        if (j < n) {
            int d = dst[base + j];
            myDst[k] = d; mySrc[k] = src[base + j]; myEw[k] = ew[base + j];
            atomicAdd(&lhist[d >> 9], 1);
        } else myDst[k] = -1;
    }
    __syncthreads();
    // exclusive scan of lhist (512 entries, 512 threads)
    int hv = lhist[t];
    tmp[t] = hv;
    __syncthreads();
    for (int off = 1; off < NBUCK; off <<= 1) {
        int v = (t >= off) ? tmp[t - off] : 0;
        __syncthreads();
        tmp[t] += v;
        __syncthreads();
    }
    lbase[t] = tmp[t] - hv;
    gbase[t] = hv ? atomicAdd(&bucketCursor[t], hv) : 0;
    __syncthreads();
    // stage into LDS, sorted by bucket; pack (src | ldst<<18, ew)
#pragma unroll
    for (int k = 0; k < APT; ++k) {
        int d = myDst[k];
        if (d >= 0) {
            int b = d >> 9;
            int p = lbase[b] + atomicAdd(&lcur[b], 1);
            stag[p] = make_int2(mySrc[k] | ((d & 511) << 18), __float_as_int(myEw[k]));
            sbuck[p] = (unsigned short)b;
        }
    }
    __syncthreads();
    // write out: consecutive j -> consecutive addresses within bucket runs
    for (int j = t; j < n; j += 512) {
        int b = sbuck[j];
        coarse[(size_t)b * BCAP + gbase[b] + (j - lbase[b])] = stag[j];
    }
}

// --- scan bucket counts -> bucket bases (1 block x 512) ------------------
__global__ void bscan_kernel(const int* __restrict__ bucketCursor,
                             int* __restrict__ bucketBase, int* __restrict__ row,
                             int N, int E) {
    __shared__ int s[NBUCK];
    int t = threadIdx.x;
    int v = bucketCursor[t];
    s[t] = v;
    __syncthreads();
    for (int off = 1; off < NBUCK; off <<= 1) {
        int x = (t >= off) ? s[t - off] : 0;
        __syncthreads();
        s[t] += x;
        __syncthreads();
    }
    bucketBase[t] = s[t] - v;
    if (t == 0) row[N] = E;
}

// --- Pass B: LDS-staged (ld,tile16) counting sort; coalesced writeout ----
// key = (ld<<4)|tile -> node-major: each node's 16 tile-runs contiguous.
__global__ __launch_bounds__(512, 2) void
binB_kernel(const int* __restrict__ bucketCursor, const int* __restrict__ bucketBase,
            const int2* __restrict__ coarse, int2* __restrict__ edata,
            int* __restrict__ row, float* __restrict__ dinv,
            uint4* __restrict__ tcnt) {
    __shared__ int2 sedata[BCAP];          // 80 KB sort staging
    __shared__ int loff[NBUCK * NTILE];    // 32 KB counts -> offsets -> cursors
    __shared__ int tmp[512];
    int b = blockIdx.x, t = threadIdx.x;
    for (int i = t; i < NBUCK * NTILE; i += 512) loff[i] = 0;
    __syncthreads();
    int cnt = bucketCursor[b];
    int gb  = bucketBase[b];
    const int2* cb = coarse + (size_t)b * BCAP;
    int2 myE[RCAP]; int myKey[RCAP];
#pragma unroll
    for (int k = 0; k < RCAP; ++k) {
        int j = t + k * 512;               // coalesced
        if (j < cnt) {
            int2 e = cb[j];
            myE[k] = e;
            myKey[k] = (((e.x >> 18) & 511) << 4) | ((e.x & 0x3FFFF) >> TSH);
            atomicAdd(&loff[myKey[k]], 1);
        } else myKey[k] = -1;
    }
    __syncthreads();
    // exclusive scan over 8192 (thread t owns node t's 16 tile-bins)
    int base16 = t * 16, s = 0;
#pragma unroll
    for (int k = 0; k < 16; ++k) s += loff[base16 + k];
    tmp[t] = s;
    __syncthreads();
    for (int off = 1; off < 512; off <<= 1) {
        int v = (t >= off) ? tmp[t - off] : 0;
        __syncthreads();
        tmp[t] += v;
        __syncthreads();
    }
    int run = tmp[t] - s;
    int o[17];
#pragma unroll
    for (int k = 0; k < 16; ++k) { int v = loff[base16 + k]; o[k] = run; loff[base16 + k] = run; run += v; }
    o[16] = run;                           // end of node t's edge range
    __syncthreads();
    int node = b * 512 + t;
    row[node] = gb + o[0];
    uint4 p0, p1;
    p0.x = (unsigned)(o[1] - o[0])  | ((unsigned)(o[2] - o[1])  << 16);
    p0.y = (unsigned)(o[3] - o[2])  | ((unsigned)(o[4] - o[3])  << 16);
    p0.z = (unsigned)(o[5] - o[4])  | ((unsigned)(o[6] - o[5])  << 16);
    p0.w = (unsigned)(o[7] - o[6])  | ((unsigned)(o[8] - o[7])  << 16);
    p1.x = (unsigned)(o[9] - o[8])  | ((unsigned)(o[10] - o[9]) << 16);
    p1.y = (unsigned)(o[11] - o[10]) | ((unsigned)(o[12] - o[11]) << 16);
    p1.z = (unsigned)(o[13] - o[12]) | ((unsigned)(o[14] - o[13]) << 16);
    p1.w = (unsigned)(o[15] - o[14]) | ((unsigned)(o[16] - o[15]) << 16);
    tcnt[2 * node + 0] = p0;
    tcnt[2 * node + 1] = p1;
    // place into LDS staging (loff is the moving cursor)
#pragma unroll
    for (int k = 0; k < RCAP; ++k) {
        if (myKey[k] >= 0) {
            int pos = atomicAdd(&loff[myKey[k]], 1);
            sedata[pos] = make_int2(myE[k].x & 0x3FFFF, myE[k].y);
        }
    }
    __syncthreads();
    // coalesced streaming writeout
    for (int j = t; j < cnt; j += 512) edata[gb + j] = sedata[j];
    // deg = sum of ew over this node's contiguous LDS-resident run
    float dsum = 0.f;
    for (int j = o[0]; j < o[16]; ++j) dsum += __int_as_float(sedata[j].y);
    dinv[node] = rsqrtf(1.0f + dsum);      // +1 = self-loop weight
}

// --- pack: Xp[i] = (x0, x1, x2, dinv) -- the 16B aggA gather operand -----
__global__ void pack_kernel(const float* __restrict__ X, const float* __restrict__ dinv,
                            float4* __restrict__ Xp, int N) {
    int i = blockIdx.x * blockDim.x + threadIdx.x;
    if (i >= N) return;
    Xp[i] = make_float4(X[3 * i], X[3 * i + 1], X[3 * i + 2], dinv[i]);
}

// --- agg pass 1: 16-tile phased 16B-gather recompute, 4-deep batched; ---
// fused node2. 512 threads = 128 node-groups x 4 lanes; nodes (i, i+128).
__global__ __launch_bounds__(512) void
aggA_kernel(const int* __restrict__ row, const uint4* __restrict__ tcnt,
            const int2* __restrict__ edata, const float4* __restrict__ Xp,
            const float* __restrict__ W1, const float* __restrict__ b1,
            const float* __restrict__ W2, float* __restrict__ h2) {
    __shared__ float w1s[48];
    __shared__ float w[256];
    __shared__ float bb[16];
    __shared__ float sx[128][17];
    int t = threadIdx.x;
    if (t < 256) w[t] = W2[t];
    else if (t < 272) bb[t - 256] = b1[t - 256];
    else if (t >= 288 && t < 336) w1s[t - 288] = W1[t - 288];
    __syncthreads();
    int ln = t >> 2, l = t & 3;
    float w1r0[4], w1r1[4], w1r2[4];
#pragma unroll
    for (int c = 0; c < 4; ++c) {
        w1r0[c] = w1s[0 * 16 + 4 * l + c];
        w1r1[c] = w1s[1 * 16 + 4 * l + c];
        w1r2[c] = w1s[2 * 16 + 4 * l + c];
    }
    int iA = blockIdx.x * 256 + ln, iB = iA + 128;
    int eA = row[iA], eB = row[iB];
    uint4 cA0 = tcnt[2 * iA], cA1 = tcnt[2 * iA + 1];
    uint4 cB0 = tcnt[2 * iB], cB1 = tcnt[2 * iB + 1];
    unsigned ca[8] = {cA0.x, cA0.y, cA0.z, cA0.w, cA1.x, cA1.y, cA1.z, cA1.w};
    unsigned cb8[8] = {cB0.x, cB0.y, cB0.z, cB0.w, cB1.x, cB1.y, cB1.z, cB1.w};
    float4 xpA = Xp[iA], xpB = Xp[iB];
    float diA = xpA.w, diB = xpB.w;
    float accA[4], accB[4];
#pragma unroll
    for (int c = 0; c < 4; ++c) {   // self-loop seed: h'_i = (X_i@W1)*dinv_i
        accA[c] = (xpA.x * w1r0[c] + xpA.y * w1r1[c] + xpA.z * w1r2[c]) * diA;
        accB[c] = (xpB.x * w1r0[c] + xpB.y * w1r1[c] + xpB.z * w1r2[c]) * diB;
    }
#pragma unroll
    for (int tt = 0; tt < NTILE; ++tt) {
        int nA = (ca[tt >> 1] >> ((tt & 1) * 16)) & 0xFFFF;
        int nB = (cb8[tt >> 1] >> ((tt & 1) * 16)) & 0xFFFF;
        while (nA > 0) {                      // 4-deep batched gather
            int j1 = min(1, nA - 1), j2 = min(2, nA - 1), j3 = min(3, nA - 1);
            int2 e0 = edata[eA], e1 = edata[eA + j1],
                 e2 = edata[eA + j2], e3 = edata[eA + j3];
            float4 x0 = Xp[e0.x], x1 = Xp[e1.x], x2 = Xp[e2.x], x3 = Xp[e3.x];
            float g0 = __int_as_float(e0.y) * x0.w;
            float g1 = (nA > 1) ? __int_as_float(e1.y) * x1.w : 0.f;
            float g2 = (nA > 2) ? __int_as_float(e2.y) * x2.w : 0.f;
            float g3 = (nA > 3) ? __int_as_float(e3.y) * x3.w : 0.f;
            float s0 = x0.x * g0 + x1.x * g1 + x2.x * g2 + x3.x * g3;
            float s1 = x0.y * g0 + x1.y * g1 + x2.y * g2 + x3.y * g3;
            float s2 = x0.z * g0 + x1.z * g1 + x2.z * g2 + x3.z * g3;
#pragma unroll
            for (int c = 0; c < 4; ++c)
                accA[c] += s0 * w1r0[c] + s1 * w1r1[c] + s2 * w1r2[c];
            int m = min(nA, 4); eA += m; nA -= m;
        }
        while (nB > 0) {
            int j1 = min(1, nB - 1), j2 = min(2, nB - 1), j3 = min(3, nB - 1);
            int2 e0 = edata[eB], e1 = edata[eB + j1],
                 e2 = edata[eB + j2], e3 = edata[eB + j3];
            float4 x0 = Xp[e0.x], x1 = Xp[e1.x], x2 = Xp[e2.x], x3 = Xp[e3.x];
            float g0 = __int_as_float(e0.y) * x0.w;
            float g1 = (nB > 1) ? __int_as_float(e1.y) * x1.w : 0.f;
            float g2 = (nB > 2) ? __int_as_float(e2.y) * x2.w : 0.f;
            float g3 = (nB > 3) ? __int_as_float(e3.y) * x3.w : 0.f;
            float s0 = x0.x * g0 + x1.x * g1 + x2.x * g2 + x3.x * g3;
            float s1 = x0.y * g0 + x1.y * g1 + x2.y * g2 + x3.y * g3;
            float s2 = x0.z * g0 + x1.z * g1 + x2.z * g2 + x3.z * g3;
#pragma unroll
            for (int c = 0; c < 4; ++c)
                accB[c] += s0 * w1r0[c] + s1 * w1r1[c] + s2 * w1r2[c];
            int m = min(nB, 4); eB += m; nB -= m;
        }
        __syncthreads();
    }
    // fused node2: x = leaky(di*acc + b1); h2' = (x@W2)*di (LDS transpose)
    sx[ln][4 * l + 0] = leaky(diA * accA[0] + bb[4 * l + 0]);
    sx[ln][4 * l + 1] = leaky(diA * accA[1] + bb[4 * l + 1]);
    sx[ln][4 * l + 2] = leaky(diA * accA[2] + bb[4 * l + 2]);
    sx[ln][4 * l + 3] = leaky(diA * accA[3] + bb[4 * l + 3]);
    __syncthreads();
    {
        float a0 = 0.f, a1 = 0.f, a2 = 0.f, a3 = 0.f;
#pragma unroll
        for (int q = 0; q < 16; ++q) {
            float xv = sx[ln][q];
            a0 += xv * w[q * 16 + 4 * l + 0];
            a1 += xv * w[q * 16 + 4 * l + 1];
            a2 += xv * w[q * 16 + 4 * l + 2];
            a3 += xv * w[q * 16 + 4 * l + 3];
        }
        ((float4*)h2)[(size_t)iA * 4 + l] = make_float4(a0 * diA, a1 * diA, a2 * diA, a3 * diA);
    }
    __syncthreads();
    sx[ln][4 * l + 0] = leaky(diB * accB[0] + bb[4 * l + 0]);
    sx[ln][4 * l + 1] = leaky(diB * accB[1] + bb[4 * l + 1]);
    sx[ln][4 * l + 2] = leaky(diB * accB[2] + bb[4 * l + 2]);
    sx[ln][4 * l + 3] = leaky(diB * accB[3] + bb[4 * l + 3]);
    __syncthreads();
    {
        float a0 = 0.f, a1 = 0.f, a2 = 0.f, a3 = 0.f;
#pragma unroll
        for (int q = 0; q < 16; ++q) {
            float xv = sx[ln][q];
            a0 += xv * w[q * 16 + 4 * l + 0];
            a1 += xv * w[q * 16 + 4 * l + 1];
            a2 += xv * w[q * 16 + 4 * l + 2];
            a3 += xv * w[q * 16 + 4 * l + 3];
        }
        ((float4*)h2)[(size_t)iB * 4 + l] = make_float4(a0 * diB, a1 * diB, a2 * diB, a3 * diB);
    }
}

// --- agg pass 2: 16-tile phased 64B gather, 4-deep batched ---------------
__global__ __launch_bounds__(512) void
aggB_kernel(const int* __restrict__ row, const uint4* __restrict__ tcnt,
            const int2* __restrict__ edata, const float* __restrict__ dinv,
            const float* __restrict__ h2prime, float* __restrict__ agg2) {
    int t = threadIdx.x;
    int ln = t >> 2, l = t & 3;
    int iA = blockIdx.x * 256 + ln, iB = iA + 128;
    const float4* hp = (const float4*)h2prime;
    int eA = row[iA], eB = row[iB];
    uint4 cA0 = tcnt[2 * iA], cA1 = tcnt[2 * iA + 1];
    uint4 cB0 = tcnt[2 * iB], cB1 = tcnt[2 * iB + 1];
    unsigned ca[8] = {cA0.x, cA0.y, cA0.z, cA0.w, cA1.x, cA1.y, cA1.z, cA1.w};
    unsigned cb8[8] = {cB0.x, cB0.y, cB0.z, cB0.w, cB1.x, cB1.y, cB1.z, cB1.w};
    float diA = dinv[iA], diB = dinv[iB];
    float4 accA = hp[(size_t)iA * 4 + l];    // self-loop seed (h2')
    float4 accB = hp[(size_t)iB * 4 + l];
#pragma unroll
    for (int tt = 0; tt < NTILE; ++tt) {
        int nA = (ca[tt >> 1] >> ((tt & 1) * 16)) & 0xFFFF;
        int nB = (cb8[tt >> 1] >> ((tt & 1) * 16)) & 0xFFFF;
        while (nA > 0) {                      // 4-deep batched gather
            int j1 = min(1, nA - 1), j2 = min(2, nA - 1), j3 = min(3, nA - 1);
            int2 e0 = edata[eA], e1 = edata[eA + j1],
                 e2 = edata[eA + j2], e3 = edata[eA + j3];
            float4 v0 = hp[(size_t)e0.x * 4 + l], v1 = hp[(size_t)e1.x * 4 + l],
                   v2 = hp[(size_t)e2.x * 4 + l], v3 = hp[(size_t)e3.x * 4 + l];
            float w0 = __int_as_float(e0.y);
            float w1 = (nA > 1) ? __int_as_float(e1.y) : 0.f;
            float w2 = (nA > 2) ? __int_as_float(e2.y) : 0.f;
            float w3 = (nA > 3) ? __int_as_float(e3.y) : 0.f;
            accA.x += v0.x * w0 + v1.x * w1 + v2.x * w2 + v3.x * w3;
            accA.y += v0.y * w0 + v1.y * w1 + v2.y * w2 + v3.y * w3;
            accA.z += v0.z * w0 + v1.z * w1 + v2.z * w2 + v3.z * w3;
            accA.w += v0.w * w0 + v1.w * w1 + v2.w * w2 + v3.w * w3;
            int m = min(nA, 4); eA += m; nA -= m;
        }
        while (nB > 0) {
            int j1 = min(1, nB - 1), j2 = min(2, nB - 1), j3 = min(3, nB - 1);
            int2 e0 = edata[eB], e1 = edata[eB + j1],
                 e2 = edata[eB + j2], e3 = edata[eB + j3];
            float4 v0 = hp[(size_t)e0.x * 4 + l], v1 = hp[(size_t)e1.x * 4 + l],
                   v2 = hp[(size_t)e2.x * 4 + l], v3 = hp[(size_t)e3.x * 4 + l];
            float w0 = __int_as_float(e0.y);
            float w1 = (nB > 1) ? __int_as_float(e1.y) : 0.f;
            float w2 = (nB > 2) ? __int_as_float(e2.y) : 0.f;
            float w3 = (nB > 3) ? __int_as_float(e3.y) : 0.f;
            accB.x += v0.x * w0 + v1.x * w1 + v2.x * w2 + v3.x * w3;
            accB.y += v0.y * w0 + v1.y * w1 + v2.y * w2 + v3.y * w3;
            accB.z += v0.z * w0 + v1.z * w1 + v2.z * w2 + v3.z * w3;
            accB.w += v0.w * w0 + v1.w * w1 + v2.w * w2 + v3.w * w3;
            int m = min(nB, 4); eB += m; nB -= m;
        }
        __syncthreads();
    }
    ((float4*)agg2)[(size_t)iA * 4 + l] =
        make_float4(accA.x * diA, accA.y * diA, accA.z * diA, accA.w * diA);
    ((float4*)agg2)[(size_t)iB * 4 + l] =
        make_float4(accB.x * diB, accB.y * diB, accB.z * diB, accB.w * diB);
}

// --- tiny MLP head: 16 ->16 ->16 ->2 -------------------------------------
__device__ void head_mlp(const float* pooled,
                         const float* __restrict__ Wa, const float* __restrict__ ba,
                         const float* __restrict__ Wb, const float* __restrict__ bb,
                         const float* __restrict__ Wc, const float* __restrict__ bc,
                         float* o) {
    float t[16], u[16];
#pragma unroll
    for (int f = 0; f < 16; ++f) {
        float a = ba[f];
        for (int k = 0; k < 16; ++k) a += pooled[k] * Wa[k * 16 + f];
        t[f] = leaky(a);
    }
#pragma unroll
    for (int f = 0; f < 16; ++f) {
        float a = bb[f];
        for (int k = 0; k < 16; ++k) a += t[k] * Wb[k * 16 + f];
        u[f] = leaky(a);
    }
    float o0 = bc[0], o1 = bc[1];
    for (int k = 0; k < 16; ++k) { o0 += u[k] * Wc[2 * k]; o1 += u[k] * Wc[2 * k + 1]; }
    o[0] = o0; o[1] = o1;
}

// --- pool (block per graph; Batching sorted -> binary search) + heads ----
__global__ void pool_head_kernel(const float* __restrict__ agg2, const float* __restrict__ b2,
                                 const int* __restrict__ batching, int N,
                                 const float* __restrict__ Wp1, const float* __restrict__ bp1,
                                 const float* __restrict__ Wp2, const float* __restrict__ bp2,
                                 const float* __restrict__ Wp3, const float* __restrict__ bp3,
                                 const float* __restrict__ Wt1, const float* __restrict__ bt1,
                                 const float* __restrict__ Wt2, const float* __restrict__ bt2,
                                 const float* __restrict__ Wt3, const float* __restrict__ bt3,
                                 float* __restrict__ out) {
    int g = blockIdx.x;
    __shared__ int bounds[2];
    if (threadIdx.x < 2) {
        int v = g + (int)threadIdx.x;
        int lo = 0, hi = N;
        while (lo < hi) { int m = (lo + hi) >> 1; if (batching[m] < v) lo = m + 1; else hi = m; }
        bounds[threadIdx.x] = lo;
    }
    __syncthreads();
    int lo = bounds[0], hi = bounds[1];
    int f = threadIdx.x & 15, r = threadIdx.x >> 4;    // 16 rows x 16 features
    float bf = b2[f];
    float acc = 0.f;
    for (int i = lo + r; i < hi; i += 16) acc += leaky(agg2[(size_t)i * 16 + f] + bf);
    __shared__ float red[16][17];
    red[r][f] = acc;
    __syncthreads();
    __shared__ float pooled[16];
    if (r == 0) {
        float s = 0.f;
#pragma unroll
        for (int k = 0; k < 16; ++k) s += red[k][f];
        pooled[f] = s / fmaxf((float)(hi - lo), 1.0f);
    }
    __syncthreads();
    if (threadIdx.x == 0) {
        float o[2];
        head_mlp(pooled, Wp1, bp1, Wp2, bp2, Wp3, bp3, o);
        out[4 * g + 0] = o[0]; out[4 * g + 1] = o[1];
    } else if (threadIdx.x == 1) {
        float o[2];
        head_mlp(pooled, Wt1, bt1, Wt2, bt2, Wt3, bt3, o);
        out[4 * g + 2] = o[0]; out[4 * g + 3] = o[1];
    }
}

extern "C" void kernel_launch(void* const* d_in, const int* in_sizes, int n_in,
                              void* d_out, int out_size, void* d_ws, size_t ws_size,
                              hipStream_t stream) {
    const float* X        = (const float*)d_in[0];
    const int*   ei       = (const int*)d_in[1];
    const float* ew       = (const float*)d_in[2];
    const int*   batching = (const int*)d_in[3];
    const float* W1  = (const float*)d_in[5];  const float* b1  = (const float*)d_in[6];
    const float* W2  = (const float*)d_in[7];  const float* b2  = (const float*)d_in[8];
    const float* Wp1 = (const float*)d_in[9];  const float* bp1 = (const float*)d_in[10];
    const float* Wp2 = (const float*)d_in[11]; const float* bp2 = (const float*)d_in[12];
    const float* Wp3 = (const float*)d_in[13]; const float* bp3 = (const float*)d_in[14];
    const float* Wt1 = (const float*)d_in[15]; const float* bt1 = (const float*)d_in[16];
    const float* Wt2 = (const float*)d_in[17]; const float* bt2 = (const float*)d_in[18];
    const float* Wt3 = (const float*)d_in[19]; const float* bt3 = (const float*)d_in[20];

    const int N = in_sizes[3];        // 262144 = 512 * 512
    const int E = in_sizes[2];        // 4194304
    const int G = out_size / 4;       // 1024
    const int* src = ei;
    const int* dst = ei + E;

    char* ws = (char*)d_ws;
    size_t off = 0;
    int2*  edata = (int2*)(ws + off);  off += (size_t)E * 8;              // 32 MB fine CSR
    char*  regionA = ws + off;         off += (size_t)N * 64 * 3;         // 48 MB
    // regionA phase 1: coarse buckets (40 MB); phase 2: h2' | agg2 | Xp
    // (pack/aggA run only after binB has consumed coarse)
    int2*  coarse = (int2*)regionA;
    float* h2     = (float*)regionA;
    float* agg2   = (float*)(regionA + (size_t)N * 64);
    float4* Xp    = (float4*)(regionA + (size_t)N * 128);                 // 4 MB
    int*   bucketCursor = (int*)(ws + off); off += NBUCK * 4;
    int*   bucketBase   = (int*)(ws + off); off += NBUCK * 4;
    int*   row   = (int*)(ws + off);   off += (size_t)(N + 4) * 4;
    float* dinv  = (float*)(ws + off); off += (size_t)N * 4;
    uint4* tcnt  = (uint4*)(ws + off); off += (size_t)N * 32;             // 8 MB (16 tiles)
    float* out   = (float*)d_out;

    hipMemsetAsync(bucketCursor, 0, NBUCK * 4, stream);

    const int tb = 256;
    binA_kernel<<<(E + CHUNK - 1) / CHUNK, 512, 0, stream>>>(src, dst, ew, bucketCursor, coarse, E);
    bscan_kernel<<<1, NBUCK, 0, stream>>>(bucketCursor, bucketBase, row, N, E);
    binB_kernel<<<NBUCK, 512, 0, stream>>>(bucketCursor, bucketBase, coarse, edata, row, dinv, tcnt);
    pack_kernel<<<(N + tb - 1) / tb, tb, 0, stream>>>(X, dinv, Xp, N);
    aggA_kernel<<<N / 256, 512, 0, stream>>>(row, tcnt, edata, Xp, W1, b1, W2, h2);
    aggB_kernel<<<N / 256, 512, 0, stream>>>(row, tcnt, edata, dinv, h2, agg2);
    pool_head_kernel<<<G, tb, 0, stream>>>(agg2, b2, batching, N,
                                           Wp1, bp1, Wp2, bp2, Wp3, bp3,
                                           Wt1, bt1, Wt2, bt2, Wt3, bt3, out);
}

// Round 13
// 353.747 us; speedup vs baseline: 1.2136x; 1.0984x over previous
//
#include <hip/hip_runtime.h>

// GCN: 2x GCNConv(sym-norm, self-loops) + mean-pool + 2 MLP heads.
// R15: exact revert to R7's proven 348us structure (6 consecutive agg
// experiments all regressed: interleave R8, batch4 R9, batch4+NT R10,
// NT-load R10, LDS-stream R11, 16-tile+batch4 R12) + launch-count cut:
//  - bscan ELIMINATED: binB reserves its edata range via one global
//    atomicAdd (bucket order irrelevant; per-node edge order unchanged
//    -> bitwise-identical output).
//  - pack ELIMINATED: binB writes Xp=(x0,x1,x2,dinv) directly (Xp now in
//    dedicated ws, no aliasing with coarse); dinv array deleted (aggB
//    reads Xp.w).
// 8 dispatches -> 6. Carried lessons: tile-phased lockstep sweep (R4/R5),
// 16B Xp recompute operand (R7), plain loads only (R6/R10: NT toxic both
// directions here), LDS sorts + coalesced writeout (R3/R4), no float LDS
// atomics (R2), sequential A-then-B run loops (R8), binA CHUNK=8192 (R7).

#define NBUCK 512          // coarse buckets = dst >> 9
#define BCAP  10240        // slack capacity per bucket (mean 8192, sigma ~90)
#define CHUNK 8192         // edges per pass-A block (16 per bucket avg)
#define APT   16           // edges per thread in binA (CHUNK/512)
#define NTILE 8            // src tiles = src >> 15
#define TSH   15
#define RCAP  20           // BCAP/512 register-staged edges per thread

__device__ __forceinline__ float leaky(float x) { return x > 0.f ? x : 0.01f * x; }

// --- Pass A: bin edges by dst>>9 into slack-capacity coarse buckets ------
__global__ __launch_bounds__(512) void
binA_kernel(const int* __restrict__ src, const int* __restrict__ dst,
            const float* __restrict__ ew, int* __restrict__ bucketCursor,
            int2* __restrict__ coarse, int E) {
    __shared__ int lhist[NBUCK], lbase[NBUCK], lcur[NBUCK], gbase[NBUCK];
    __shared__ int tmp[NBUCK];
    __shared__ int2 stag[CHUNK];              // 64 KB
    __shared__ unsigned short sbuck[CHUNK];   // 16 KB
    int t = threadIdx.x;
    int base = blockIdx.x * CHUNK;
    lhist[t] = 0; lcur[t] = 0;
    __syncthreads();
    int n = min(CHUNK, E - base);
    int myDst[APT], mySrc[APT]; float myEw[APT];
#pragma unroll
    for (int k = 0; k < APT; ++k) {
        int j = t + k * 512;                  // coalesced
        if (j < n) {
            int d = dst[base + j];
            myDst[k] = d; mySrc[k] = src[base + j]; myEw[k] = ew[base + j];
            atomicAdd(&lhist[d >> 9], 1);
        } else myDst[k] = -1;
    }
    __syncthreads();
    // exclusive scan of lhist (512 entries, 512 threads)
    int hv = lhist[t];
    tmp[t] = hv;
    __syncthreads();
    for (int off = 1; off < NBUCK; off <<= 1) {
        int v = (t >= off) ? tmp[t - off] : 0;
        __syncthreads();
        tmp[t] += v;
        __syncthreads();
    }
    lbase[t] = tmp[t] - hv;
    gbase[t] = hv ? atomicAdd(&bucketCursor[t], hv) : 0;
    __syncthreads();
    // stage into LDS, sorted by bucket; pack (src | ldst<<18, ew)
#pragma unroll
    for (int k = 0; k < APT; ++k) {
        int d = myDst[k];
        if (d >= 0) {
            int b = d >> 9;
            int p = lbase[b] + atomicAdd(&lcur[b], 1);
            stag[p] = make_int2(mySrc[k] | ((d & 511) << 18), __float_as_int(myEw[k]));
            sbuck[p] = (unsigned short)b;
        }
    }
    __syncthreads();
    // write out: consecutive j -> consecutive addresses within bucket runs
    for (int j = t; j < n; j += 512) {
        int b = sbuck[j];
        coarse[(size_t)b * BCAP + gbase[b] + (j - lbase[b])] = stag[j];
    }
}

// --- Pass B: LDS-staged (ld,tile) counting sort; coalesced writeout ------
// Reserves its global edata range via one atomicAdd (bscan eliminated);
// emits row, tcnt, and Xp=(x0,x1,x2,dinv) (pack eliminated).
__global__ __launch_bounds__(512, 2) void
binB_kernel(const int* __restrict__ bucketCursor, int* __restrict__ globalCursor,
            const int2* __restrict__ coarse, int2* __restrict__ edata,
            int* __restrict__ row, const float* __restrict__ X,
            float4* __restrict__ Xp, uint4* __restrict__ tcnt) {
    __shared__ int2 sedata[BCAP];         // 80 KB sort staging
    __shared__ int loff[NBUCK * NTILE];   // counts -> offsets -> cursors
    __shared__ int tmp[512];
    __shared__ int gbs;
    int b = blockIdx.x, t = threadIdx.x;
    for (int i = t; i < NBUCK * NTILE; i += 512) loff[i] = 0;
    __syncthreads();
    int cnt = bucketCursor[b];
    if (t == 0) gbs = atomicAdd(globalCursor, cnt);   // unordered range reserve
    const int2* cb = coarse + (size_t)b * BCAP;
    int2 myE[RCAP]; int myKey[RCAP];
#pragma unroll
    for (int k = 0; k < RCAP; ++k) {
        int j = t + k * 512;               // coalesced
        if (j < cnt) {
            int2 e = cb[j];
            myE[k] = e;
            myKey[k] = (((e.x >> 18) & 511) << 3) | ((e.x & 0x3FFFF) >> TSH);
            atomicAdd(&loff[myKey[k]], 1);
        } else myKey[k] = -1;
    }
    __syncthreads();
    // exclusive scan over 4096 (thread t owns node t's 8 tile-bins)
    int base8 = t * 8, s = 0;
#pragma unroll
    for (int k = 0; k < 8; ++k) s += loff[base8 + k];
    tmp[t] = s;
    __syncthreads();
    for (int off = 1; off < 512; off <<= 1) {
        int v = (t >= off) ? tmp[t - off] : 0;
        __syncthreads();
        tmp[t] += v;
        __syncthreads();
    }
    int run = tmp[t] - s;
    int o[9];
#pragma unroll
    for (int k = 0; k < 8; ++k) { int v = loff[base8 + k]; o[k] = run; loff[base8 + k] = run; run += v; }
    o[8] = run;                            // end of node t's edge range
    __syncthreads();
    int gb = gbs;
    int node = b * 512 + t;
    row[node] = gb + o[0];
    uint4 p;
    p.x = (unsigned)(o[1] - o[0]) | ((unsigned)(o[2] - o[1]) << 16);
    p.y = (unsigned)(o[3] - o[2]) | ((unsigned)(o[4] - o[3]) << 16);
    p.z = (unsigned)(o[5] - o[4]) | ((unsigned)(o[6] - o[5]) << 16);
    p.w = (unsigned)(o[7] - o[6]) | ((unsigned)(o[8] - o[7]) << 16);
    tcnt[node] = p;
    // place into LDS staging (loff is the moving cursor)
#pragma unroll
    for (int k = 0; k < RCAP; ++k) {
        if (myKey[k] >= 0) {
            int pos = atomicAdd(&loff[myKey[k]], 1);
            sedata[pos] = make_int2(myE[k].x & 0x3FFFF, myE[k].y);
        }
    }
    __syncthreads();
    // coalesced streaming writeout
    for (int j = t; j < cnt; j += 512) edata[gb + j] = sedata[j];
    // deg = sum of ew over this node's LDS-resident run
    float dsum = 0.f;
    for (int j = o[0]; j < o[8]; ++j) dsum += __int_as_float(sedata[j].y);
    float di = rsqrtf(1.0f + dsum);        // +1 = self-loop weight
    Xp[node] = make_float4(X[3 * node], X[3 * node + 1], X[3 * node + 2], di);
}

// --- agg pass 1: tile-phased 16B-gather recompute; fused node2 -----------
// 512 threads = 128 node-groups x 4 lanes; 2 nodes per group (i, i+128).
// All 1024 blocks co-resident (4/CU); per-tile barrier keeps each XCD's
// gathers inside a 0.5MB Xp window.
__global__ __launch_bounds__(512) void
aggA_kernel(const int* __restrict__ row, const uint4* __restrict__ tcnt,
            const int2* __restrict__ edata, const float4* __restrict__ Xp,
            const float* __restrict__ W1, const float* __restrict__ b1,
            const float* __restrict__ W2, float* __restrict__ h2) {
    __shared__ float w1s[48];
    __shared__ float w[256];
    __shared__ float bb[16];
    __shared__ float sx[128][17];
    int t = threadIdx.x;
    if (t < 256) w[t] = W2[t];
    else if (t < 272) bb[t - 256] = b1[t - 256];
    else if (t >= 288 && t < 336) w1s[t - 288] = W1[t - 288];
    __syncthreads();
    int ln = t >> 2, l = t & 3;
    // my 4 output features' W1 columns (3 input rows)
    float w1r0[4], w1r1[4], w1r2[4];
#pragma unroll
    for (int c = 0; c < 4; ++c) {
        w1r0[c] = w1s[0 * 16 + 4 * l + c];
        w1r1[c] = w1s[1 * 16 + 4 * l + c];
        w1r2[c] = w1s[2 * 16 + 4 * l + c];
    }
    int iA = blockIdx.x * 256 + ln, iB = iA + 128;
    int eA = row[iA], eB = row[iB];
    uint4 cAv = tcnt[iA], cBv = tcnt[iB];
    unsigned ca[4] = {cAv.x, cAv.y, cAv.z, cAv.w};
    unsigned cb[4] = {cBv.x, cBv.y, cBv.z, cBv.w};
    float4 xpA = Xp[iA], xpB = Xp[iB];
    float diA = xpA.w, diB = xpB.w;
    float accA[4], accB[4];
#pragma unroll
    for (int c = 0; c < 4; ++c) {   // self-loop seed: h'_i = (X_i@W1)*dinv_i
        accA[c] = (xpA.x * w1r0[c] + xpA.y * w1r1[c] + xpA.z * w1r2[c]) * diA;
        accB[c] = (xpB.x * w1r0[c] + xpB.y * w1r1[c] + xpB.z * w1r2[c]) * diB;
    }
#pragma unroll
    for (int tt = 0; tt < NTILE; ++tt) {
        int nA = (ca[tt >> 1] >> ((tt & 1) * 16)) & 0xFFFF;
        int nB = (cb[tt >> 1] >> ((tt & 1) * 16)) & 0xFFFF;
        for (int e = eA + nA; eA < e; ++eA) {
            int2 ed = edata[eA];
            float4 xs = Xp[ed.x];
            float f = __int_as_float(ed.y) * xs.w;
            float f0 = xs.x * f, f1 = xs.y * f, f2 = xs.z * f;
#pragma unroll
            for (int c = 0; c < 4; ++c)
                accA[c] += f0 * w1r0[c] + f1 * w1r1[c] + f2 * w1r2[c];
        }
        for (int e = eB + nB; eB < e; ++eB) {
            int2 ed = edata[eB];
            float4 xs = Xp[ed.x];
            float f = __int_as_float(ed.y) * xs.w;
            float f0 = xs.x * f, f1 = xs.y * f, f2 = xs.z * f;
#pragma unroll
            for (int c = 0; c < 4; ++c)
                accB[c] += f0 * w1r0[c] + f1 * w1r1[c] + f2 * w1r2[c];
        }
        __syncthreads();
    }
    // fused node2: x = leaky(di*acc + b1); h2' = (x@W2)*di (LDS transpose)
    sx[ln][4 * l + 0] = leaky(diA * accA[0] + bb[4 * l + 0]);
    sx[ln][4 * l + 1] = leaky(diA * accA[1] + bb[4 * l + 1]);
    sx[ln][4 * l + 2] = leaky(diA * accA[2] + bb[4 * l + 2]);
    sx[ln][4 * l + 3] = leaky(diA * accA[3] + bb[4 * l + 3]);
    __syncthreads();
    {
        float a0 = 0.f, a1 = 0.f, a2 = 0.f, a3 = 0.f;
#pragma unroll
        for (int q = 0; q < 16; ++q) {
            float xv = sx[ln][q];
            a0 += xv * w[q * 16 + 4 * l + 0];
            a1 += xv * w[q * 16 + 4 * l + 1];
            a2 += xv * w[q * 16 + 4 * l + 2];
            a3 += xv * w[q * 16 + 4 * l + 3];
        }
        ((float4*)h2)[(size_t)iA * 4 + l] = make_float4(a0 * diA, a1 * diA, a2 * diA, a3 * diA);
    }
    __syncthreads();
    sx[ln][4 * l + 0] = leaky(diB * accB[0] + bb[4 * l + 0]);
    sx[ln][4 * l + 1] = leaky(diB * accB[1] + bb[4 * l + 1]);
    sx[ln][4 * l + 2] = leaky(diB * accB[2] + bb[4 * l + 2]);
    sx[ln][4 * l + 3] = leaky(diB * accB[3] + bb[4 * l + 3]);
    __syncthreads();
    {
        float a0 = 0.f, a1 = 0.f, a2 = 0.f, a3 = 0.f;
#pragma unroll
        for (int q = 0; q < 16; ++q) {
            float xv = sx[ln][q];
            a0 += xv * w[q * 16 + 4 * l + 0];
            a1 += xv * w[q * 16 + 4 * l + 1];
            a2 += xv * w[q * 16 + 4 * l + 2];
            a3 += xv * w[q * 16 + 4 * l + 3];
        }
        ((float4*)h2)[(size_t)iB * 4 + l] = make_float4(a0 * diB, a1 * diB, a2 * diB, a3 * diB);
    }
}

// --- agg pass 2, tile-phased 64B gather (pool applies b2+leaky) ----------
__global__ __launch_bounds__(512) void
aggB_kernel(const int* __restrict__ row, const uint4* __restrict__ tcnt,
            const int2* __restrict__ edata, const float4* __restrict__ Xp,
            const float* __restrict__ h2prime, float* __restrict__ agg2) {
    int t = threadIdx.x;
    int ln = t >> 2, l = t & 3;
    int iA = blockIdx.x * 256 + ln, iB = iA + 128;
    const float4* hp = (const float4*)h2prime;
    int eA = row[iA], eB = row[iB];
    uint4 cAv = tcnt[iA], cBv = tcnt[iB];
    unsigned ca[4] = {cAv.x, cAv.y, cAv.z, cAv.w};
    unsigned cb[4] = {cBv.x, cBv.y, cBv.z, cBv.w};
    float diA = Xp[iA].w, diB = Xp[iB].w;
    float4 accA = hp[(size_t)iA * 4 + l];    // self-loop seed (h2')
    float4 accB = hp[(size_t)iB * 4 + l];
#pragma unroll
    for (int tt = 0; tt < NTILE; ++tt) {
        int nA = (ca[tt >> 1] >> ((tt & 1) * 16)) & 0xFFFF;
        int nB = (cb[tt >> 1] >> ((tt & 1) * 16)) & 0xFFFF;
        for (int e = eA + nA; eA < e; ++eA) {
            int2 ed = edata[eA];
            float ewv = __int_as_float(ed.y);
            float4 v = hp[(size_t)ed.x * 4 + l];
            accA.x += v.x * ewv; accA.y += v.y * ewv;
            accA.z += v.z * ewv; accA.w += v.w * ewv;
        }
        for (int e = eB + nB; eB < e; ++eB) {
            int2 ed = edata[eB];
            float ewv = __int_as_float(ed.y);
            float4 v = hp[(size_t)ed.x * 4 + l];
            accB.x += v.x * ewv; accB.y += v.y * ewv;
            accB.z += v.z * ewv; accB.w += v.w * ewv;
        }
        __syncthreads();
    }
    ((float4*)agg2)[(size_t)iA * 4 + l] =
        make_float4(accA.x * diA, accA.y * diA, accA.z * diA, accA.w * diA);
    ((float4*)agg2)[(size_t)iB * 4 + l] =
        make_float4(accB.x * diB, accB.y * diB, accB.z * diB, accB.w * diB);
}

// --- tiny MLP head: 16 ->16 ->16 ->2 -------------------------------------
__device__ void head_mlp(const float* pooled,
                         const float* __restrict__ Wa, const float* __restrict__ ba,
                         const float* __restrict__ Wb, const float* __restrict__ bb,
                         const float* __restrict__ Wc, const float* __restrict__ bc,
                         float* o) {
    float t[16], u[16];
#pragma unroll
    for (int f = 0; f < 16; ++f) {
        float a = ba[f];
        for (int k = 0; k < 16; ++k) a += pooled[k] * Wa[k * 16 + f];
        t[f] = leaky(a);
    }
#pragma unroll
    for (int f = 0; f < 16; ++f) {
        float a = bb[f];
        for (int k = 0; k < 16; ++k) a += t[k] * Wb[k * 16 + f];
        u[f] = leaky(a);
    }
    float o0 = bc[0], o1 = bc[1];
    for (int k = 0; k < 16; ++k) { o0 += u[k] * Wc[2 * k]; o1 += u[k] * Wc[2 * k + 1]; }
    o[0] = o0; o[1] = o1;
}

// --- pool (block per graph; Batching sorted -> binary search) + heads ----
__global__ void pool_head_kernel(const float* __restrict__ agg2, const float* __restrict__ b2,
                                 const int* __restrict__ batching, int N,
                                 const float* __restrict__ Wp1, const float* __restrict__ bp1,
                                 const float* __restrict__ Wp2, const float* __restrict__ bp2,
                                 const float* __restrict__ Wp3, const float* __restrict__ bp3,
                                 const float* __restrict__ Wt1, const float* __restrict__ bt1,
                                 const float* __restrict__ Wt2, const float* __restrict__ bt2,
                                 const float* __restrict__ Wt3, const float* __restrict__ bt3,
                                 float* __restrict__ out) {
    int g = blockIdx.x;
    __shared__ int bounds[2];
    if (threadIdx.x < 2) {
        int v = g + (int)threadIdx.x;
        int lo = 0, hi = N;
        while (lo < hi) { int m = (lo + hi) >> 1; if (batching[m] < v) lo = m + 1; else hi = m; }
        bounds[threadIdx.x] = lo;
    }
    __syncthreads();
    int lo = bounds[0], hi = bounds[1];
    int f = threadIdx.x & 15, r = threadIdx.x >> 4;    // 16 rows x 16 features
    float bf = b2[f];
    float acc = 0.f;
    for (int i = lo + r; i < hi; i += 16) acc += leaky(agg2[(size_t)i * 16 + f] + bf);
    __shared__ float red[16][17];
    red[r][f] = acc;
    __syncthreads();
    __shared__ float pooled[16];
    if (r == 0) {
        float s = 0.f;
#pragma unroll
        for (int k = 0; k < 16; ++k) s += red[k][f];
        pooled[f] = s / fmaxf((float)(hi - lo), 1.0f);
    }
    __syncthreads();
    if (threadIdx.x == 0) {
        float o[2];
        head_mlp(pooled, Wp1, bp1, Wp2, bp2, Wp3, bp3, o);
        out[4 * g + 0] = o[0]; out[4 * g + 1] = o[1];
    } else if (threadIdx.x == 1) {
        float o[2];
        head_mlp(pooled, Wt1, bt1, Wt2, bt2, Wt3, bt3, o);
        out[4 * g + 2] = o[0]; out[4 * g + 3] = o[1];
    }
}

extern "C" void kernel_launch(void* const* d_in, const int* in_sizes, int n_in,
                              void* d_out, int out_size, void* d_ws, size_t ws_size,
                              hipStream_t stream) {
    const float* X        = (const float*)d_in[0];
    const int*   ei       = (const int*)d_in[1];
    const float* ew       = (const float*)d_in[2];
    const int*   batching = (const int*)d_in[3];
    const float* W1  = (const float*)d_in[5];  const float* b1  = (const float*)d_in[6];
    const float* W2  = (const float*)d_in[7];  const float* b2  = (const float*)d_in[8];
    const float* Wp1 = (const float*)d_in[9];  const float* bp1 = (const float*)d_in[10];
    const float* Wp2 = (const float*)d_in[11]; const float* bp2 = (const float*)d_in[12];
    const float* Wp3 = (const float*)d_in[13]; const float* bp3 = (const float*)d_in[14];
    const float* Wt1 = (const float*)d_in[15]; const float* bt1 = (const float*)d_in[16];
    const float* Wt2 = (const float*)d_in[17]; const float* bt2 = (const float*)d_in[18];
    const float* Wt3 = (const float*)d_in[19]; const float* bt3 = (const float*)d_in[20];

    const int N = in_sizes[3];        // 262144 = 512 * 512
    const int E = in_sizes[2];        // 4194304
    const int G = out_size / 4;       // 1024
    const int* src = ei;
    const int* dst = ei + E;

    char* ws = (char*)d_ws;
    size_t off = 0;
    int2*  edata = (int2*)(ws + off);  off += (size_t)E * 8;              // 32 MB fine CSR
    char*  regionA = ws + off;         off += (size_t)NBUCK * BCAP * 8;   // 40 MB
    // regionA phase 1: coarse buckets (40 MB); phase 2: h2' | agg2
    int2*  coarse = (int2*)regionA;
    float* h2     = (float*)regionA;
    float* agg2   = (float*)(regionA + (size_t)N * 64);
    int*   bucketCursor = (int*)(ws + off); off += (NBUCK + 1) * 4;       // +globalCursor
    int*   globalCursor = bucketCursor + NBUCK;
    int*   row   = (int*)(ws + off);   off += (size_t)(N + 4) * 4;
    uint4* tcnt  = (uint4*)(ws + off); off += (size_t)N * 16;             // 4 MB
    float4* Xp   = (float4*)(ws + off); off += (size_t)N * 16;            // 4 MB (no aliasing)
    float* out   = (float*)d_out;

    hipMemsetAsync(bucketCursor, 0, (NBUCK + 1) * 4, stream);

    binA_kernel<<<(E + CHUNK - 1) / CHUNK, 512, 0, stream>>>(src, dst, ew, bucketCursor, coarse, E);
    binB_kernel<<<NBUCK, 512, 0, stream>>>(bucketCursor, globalCursor, coarse, edata,
                                           row, X, Xp, tcnt);
    aggA_kernel<<<N / 256, 512, 0, stream>>>(row, tcnt, edata, Xp, W1, b1, W2, h2);
    aggB_kernel<<<N / 256, 512, 0, stream>>>(row, tcnt, edata, Xp, h2, agg2);
    pool_head_kernel<<<G, 256, 0, stream>>>(agg2, b2, batching, N,
                                            Wp1, bp1, Wp2, bp2, Wp3, bp3,
                                            Wt1, bt1, Wt2, bt2, Wt3, bt3, out);
}